// Round 3
// baseline (523.881 us; speedup 1.0000x reference)
//
#include <hip/hip_runtime.h>
#include <hip/hip_fp16.h>
#include <math.h>

#define T_DIM 2048
#define K_DIM 17
#define HID   64
#define B_DIM 32

typedef short s16x8 __attribute__((ext_vector_type(8)));
typedef unsigned u32x2 __attribute__((ext_vector_type(2)));
typedef float f32x4 __attribute__((ext_vector_type(4)));
typedef _Float16 f16x2 __attribute__((ext_vector_type(2)));

// packed f32 pair -> f16 pair (1 instruction: v_cvt_pkrtz_f16_f32)
__device__ __forceinline__ unsigned pkh(float lo, float hi) {
    return __builtin_bit_cast(unsigned, __builtin_amdgcn_cvt_pkrtz(lo, hi));
}
__device__ __forceinline__ f16x2 u2h(unsigned v) {
    return __builtin_bit_cast(f16x2, v);
}
__device__ __forceinline__ unsigned h2u(f16x2 v) {
    return __builtin_bit_cast(unsigned, v);
}
__device__ __forceinline__ short f2h(float f) {          // cold path
    _Float16 h = (_Float16)f;
    return __builtin_bit_cast(short, h);
}

// COCO skeleton sparsity: column-v nonzeros of adj (incl. self).
static constexpr int NBR_PTR[18] = {0,3,6,9,11,13,17,21,24,27,29,31,34,37,40,43,45,47};
static constexpr int NBR_K[47] = {
    0,1,2,  0,1,3,  0,2,4,  1,3,  2,4,
    5,6,7,11,  5,6,8,12,  5,7,9,  6,8,10,  7,9,  8,10,
    5,11,13,  6,12,14,  11,13,15,  12,14,16,  13,15,  14,16 };
__device__ const int d_NBR_PTR[18] = {0,3,6,9,11,13,17,21,24,27,29,31,34,37,40,43,45,47};
__device__ const int d_NBR_K[47] = {
    0,1,2,  0,1,3,  0,2,4,  1,3,  2,4,
    5,6,7,11,  5,6,8,12,  5,7,9,  6,8,10,  7,9,  8,10,
    5,11,13,  6,12,14,  11,13,15,  12,14,16,  13,15,  14,16 };

// ---------------------------------------------------------------------------
// Fold GCN channel-mix into temporal conv weights (f16).
//   effT0[o][k32]  k = dt*8+cin (cin<3, dt<3), rest 0    (block1, K=32)
//   effT12[blk][o][dt*64+c]                              (blocks 2,3, K=192)
//   bnc[blk*64+o] = s/sqrt(v+eps);  bnc[192+blk*64+o] = b - m*inv
// ---------------------------------------------------------------------------
__global__ void fold_weights_kernel(
    const float* __restrict__ gw0, const float* __restrict__ gw1,
    const float* __restrict__ gw2, const float* __restrict__ tcn,
    const float* __restrict__ bns, const float* __restrict__ bnb,
    const float* __restrict__ bnm, const float* __restrict__ bnv,
    short* __restrict__ effT0, short* __restrict__ effT12,
    float* __restrict__ bnc)
{
    int tid = blockIdx.x * blockDim.x + threadIdx.x;
    int stride = gridDim.x * blockDim.x;
    for (int idx = tid; idx < 2048; idx += stride) {
        int o = idx >> 5, k = idx & 31, dt = k >> 3, cin = k & 7;
        float s = 0.f;
        if (dt < 3 && cin < 3)
            for (int m = 0; m < 64; m++)
                s += gw0[cin * 64 + m] * tcn[(o * 64 + m) * 3 + dt];
        effT0[idx] = f2h(s);
    }
    for (int idx = tid; idx < 24576; idx += stride) {
        int blk = idx / 12288;
        int r = idx - blk * 12288;
        int o = r / 192, k = r - o * 192, dt = k >> 6, c = k & 63;
        const float* gw = blk ? gw2 : gw1;
        const float* tw = tcn + (size_t)(blk + 1) * 64 * 64 * 3;
        float s = 0.f;
        for (int m = 0; m < 64; m++)
            s += gw[c * 64 + m] * tw[(o * 64 + m) * 3 + dt];
        effT12[idx] = f2h(s);
    }
    for (int i = tid; i < 192; i += stride) {
        float inv = bns[i] * rsqrtf(bnv[i] + 1e-5f);
        bnc[i] = inv;
        bnc[192 + i] = bnb[i] - bnm[i] * inv;
    }
}

// ---------------------------------------------------------------------------
// Fully fused kernel: premix + block1 + block2 + block3 + pool, all in LDS.
// 512 threads / 8 waves.  Wave->work map: each wave owns ROW-TILES x ALL 64
// output channels (4 A-frags + acc[4]) so one LDS B-read feeds 4 MFMAs
// (4x fewer ds_read_b128 than channel-split mapping; LDS pipe was ~80% busy).
// A-frags loaded per kk-half (48 VGPR) to stay under the 128-reg cap.
// LDS 72.7 KB -> 2 blocks/CU x 8 waves = 4 waves/SIMD.
// Per block: 8 output t-rows.  Halo recompute: y2 over 12 t-rows (204 kpt
// rows), y1 over 14 t-rows (238 rows), x over 16 t-rows.
// ---------------------------------------------------------------------------
__global__ __launch_bounds__(512, 4) void stgcn_fused_kernel(
    const float* __restrict__ x, const float* __restrict__ adj,
    const short* __restrict__ effT0, const short* __restrict__ effT12,
    const short* __restrict__ effW3, const float* __restrict__ bnc,
    float* __restrict__ part)
{
    __shared__ unsigned adj_h[289];                    // f16x2 broadcast pairs
    __shared__ float adj_f[289];
    __shared__ __align__(16) float xs[16 * 51];        // raw x rows t0-4..t0+11
    __shared__ __align__(16) float xtg[16 * 52];       // premixed
    __shared__ __align__(16) short y1buf[238 * 72];    // 34272 B
    __shared__ __align__(16) short y2buf[204 * 72];    // 29376 B
    float* const pr = xs;                              // pool partials alias

    const int tid = threadIdx.x;
    const int b = blockIdx.y;
    const int t0 = blockIdx.x * 8;
    const int lane = tid & 63, wave = tid >> 6;
    const int col = lane & 15, kgrp = lane >> 4;

    for (int i = tid; i < 289; i += 512) {
        float w = adj[i];
        adj_f[i] = w;
        adj_h[i] = pkh(w, w);
    }
    {   // coalesced stage of raw x rows t = t0-4 .. t0+11 (zero for OOB t)
        const float* src = x + ((size_t)b * T_DIM + t0 - 4) * 51;
        for (int i = tid; i < 816; i += 512) {
            const int row = i / 51;
            const int t = t0 - 4 + row;
            xs[i] = (t >= 0 && t < T_DIM) ? src[i] : 0.f;
        }
    }
    // block-1 A-frags: all 4 channel groups (o = cg*16 + col)
    s16x8 af1[4];
    #pragma unroll
    for (int cg = 0; cg < 4; cg++)
        af1[cg] = *(const s16x8*)(effT0 + (cg * 16 + col) * 32 + kgrp * 8);
    __syncthreads();

    // ---- premix: xtg[r][j*3+c] = sum_k adj[k][j] * xs[r][k*3+c] ----
    for (int i = tid; i < 272; i += 512) {
        const int r = (i * 241) >> 12;                 // i/17
        const int j = i - r * 17;
        const float* xp = &xs[r * 51];
        float a0 = 0.f, a1 = 0.f, a2 = 0.f;
        const int p0 = d_NBR_PTR[j], p1 = d_NBR_PTR[j + 1];
        for (int e = p0; e < p1; e++) {
            const int k = d_NBR_K[e];
            const float w = adj_f[k * 17 + j];
            a0 += w * xp[k * 3 + 0];
            a1 += w * xp[k * 3 + 1];
            a2 += w * xp[k * 3 + 2];
        }
        float* op = &xtg[r * 52 + j * 3];
        op[0] = a0; op[1] = a1; op[2] = a2;
    }
    __syncthreads();

    // ---- GEMM1: 238 rows (15 tiles, wave-owned), K=32; one B-gather per
    //      tile feeds 4 MFMAs; epilogue BN+ReLU (+t-valid zeroing) ----
    {
        f32x4 inv4[4], sh4[4];
        #pragma unroll
        for (int cg = 0; cg < 4; cg++) {
            inv4[cg] = *(const f32x4*)&bnc[cg * 16 + kgrp * 4];
            sh4[cg]  = *(const f32x4*)&bnc[192 + cg * 16 + kgrp * 4];
        }
        for (int tile = wave; tile < 15; tile += 8) {
            const int r = tile * 16 + col;
            const int me = r < 238 ? r : 237;
            const int s = (me * 241) >> 12;            // me/17
            const int j = me - s * 17;
            int4 bz = {0, 0, 0, 0};
            if (kgrp < 3) {                            // dt = kgrp
                const float* xp = &xtg[(s + kgrp) * 52 + j * 3];
                bz.x = (int)pkh(xp[0], xp[1]);
                bz.y = (int)pkh(xp[2], 0.f);
            }
            s16x8 bfr = __builtin_bit_cast(s16x8, bz);
            f32x4 acc[4];
            #pragma unroll
            for (int cg = 0; cg < 4; cg++)
                acc[cg] = __builtin_amdgcn_mfma_f32_16x16x32_f16(
                    af1[cg], bfr, (f32x4){0.f, 0.f, 0.f, 0.f}, 0, 0, 0);
            const int t = t0 - 3 + s;
            const bool valid = (t >= 0) && (t < T_DIM);
            if (r < 238) {
                #pragma unroll
                for (int cg = 0; cg < 4; cg++) {
                    float v0 = valid ? fmaxf(acc[cg][0] * inv4[cg][0] + sh4[cg][0], 0.f) : 0.f;
                    float v1 = valid ? fmaxf(acc[cg][1] * inv4[cg][1] + sh4[cg][1], 0.f) : 0.f;
                    float v2 = valid ? fmaxf(acc[cg][2] * inv4[cg][2] + sh4[cg][2], 0.f) : 0.f;
                    float v3 = valid ? fmaxf(acc[cg][3] * inv4[cg][3] + sh4[cg][3], 0.f) : 0.f;
                    u32x2 st; st[0] = pkh(v0, v1); st[1] = pkh(v2, v3);
                    *(u32x2*)&y1buf[r * 72 + cg * 16 + kgrp * 4] = st;
                }
            }
        }
    }
    __syncthreads();

    // ---- GEMM2: 204 rows (13 tiles, wave-owned: wave, wave+8), K=192.
    //      kk-halves: 12 A-frags (48 VGPR) at a time; acc[2][4] static. ----
    {
        f32x4 acc2[2][4];
        #pragma unroll
        for (int i = 0; i < 2; i++)
            #pragma unroll
            for (int cg = 0; cg < 4; cg++)
                acc2[i][cg] = (f32x4){0.f, 0.f, 0.f, 0.f};
        #pragma unroll
        for (int half = 0; half < 2; half++) {
            s16x8 af[3][4];
            #pragma unroll
            for (int kh = 0; kh < 3; kh++)
                #pragma unroll
                for (int cg = 0; cg < 4; cg++)
                    af[kh][cg] = *(const s16x8*)(effT12 +
                        (cg * 16 + col) * 192 + (half * 3 + kh) * 32 + kgrp * 8);
            #pragma unroll
            for (int i = 0; i < 2; i++) {
                const int tile = wave + 8 * i;
                if (tile < 13) {
                    const int r = tile * 16 + col;
                    const int me = r < 204 ? r : 203;
                    #pragma unroll
                    for (int kh = 0; kh < 3; kh++) {
                        const int kk = half * 3 + kh;
                        s16x8 bfr = *(const s16x8*)&y1buf[
                            (me + 17 * (kk >> 1)) * 72 + (kk & 1) * 32 + kgrp * 8];
                        #pragma unroll
                        for (int cg = 0; cg < 4; cg++)
                            acc2[i][cg] = __builtin_amdgcn_mfma_f32_16x16x32_f16(
                                af[kh][cg], bfr, acc2[i][cg], 0, 0, 0);
                    }
                }
            }
        }
        __syncthreads();                               // y1buf reads done
        // z2 -> y2buf
        #pragma unroll
        for (int i = 0; i < 2; i++) {
            const int tile = wave + 8 * i;
            const int r = tile * 16 + col;
            if (tile < 13 && r < 204) {
                #pragma unroll
                for (int cg = 0; cg < 4; cg++) {
                    u32x2 st;
                    st[0] = pkh(acc2[i][cg][0], acc2[i][cg][1]);
                    st[1] = pkh(acc2[i][cg][2], acc2[i][cg][3]);
                    *(u32x2*)&y2buf[r * 72 + cg * 16 + kgrp * 4] = st;
                }
            }
        }
    }
    __syncthreads();

    // ---- mix2 (packed f16) in-place on y2buf + y1 residual + invalid-t
    //      zeroing.  Each item (tl,o0) reads exactly the cells it writes. ----
    if (tid < 384) {
        const f16x2 zero = u2h(0u);
        const int tl = tid >> 5, o0 = (tid & 31) * 2;
        const f16x2 inv2 = u2h(pkh(bnc[64 + o0], bnc[64 + o0 + 1]));
        const f16x2 sh2  = u2h(pkh(bnc[256 + o0], bnc[256 + o0 + 1]));
        f16x2 zk[17];
        #pragma unroll
        for (int k = 0; k < 17; k++)
            zk[k] = u2h(*(const unsigned*)&y2buf[(tl * 17 + k) * 72 + o0]);
        const int t = t0 - 2 + tl;
        const bool valid = (t >= 0) && (t < T_DIM);
        #pragma unroll
        for (int v = 0; v < 17; v++) {
            f16x2 g = zero;
            #pragma unroll
            for (int e = NBR_PTR[v]; e < NBR_PTR[v + 1]; e++) {
                int k = NBR_K[e];
                g = u2h(adj_h[k * 17 + v]) * zk[k] + g;
            }
            f16x2 val = __builtin_elementwise_max(g * inv2 + sh2, zero);
            val = val + u2h(*(const unsigned*)&y1buf[
                ((tl + 1) * 17 + v) * 72 + o0]);
            *(unsigned*)&y2buf[(tl * 17 + v) * 72 + o0] =
                valid ? h2u(val) : 0u;
        }
    }
    __syncthreads();

    // ---- residual/pool pre-sum over y2 rows t0..t0+7 ----
    f16x2 rs = u2h(0u);
    if (tid < 256) {
        const int tl = tid >> 5, o0 = (tid & 31) * 2;
        #pragma unroll
        for (int v = 0; v < 17; v++)
            rs = rs + u2h(*(const unsigned*)&y2buf[((tl + 2) * 17 + v) * 72 + o0]);
    }

    // ---- GEMM3: 136 rows (9 tiles, wave-owned: wave, wave+8), K=192,
    //      DIL=2; z3 stored straight into y1buf (dead after mix2) ----
    {
        f32x4 acc3[2][4];
        #pragma unroll
        for (int i = 0; i < 2; i++)
            #pragma unroll
            for (int cg = 0; cg < 4; cg++)
                acc3[i][cg] = (f32x4){0.f, 0.f, 0.f, 0.f};
        #pragma unroll
        for (int half = 0; half < 2; half++) {
            s16x8 af[3][4];
            #pragma unroll
            for (int kh = 0; kh < 3; kh++)
                #pragma unroll
                for (int cg = 0; cg < 4; cg++)
                    af[kh][cg] = *(const s16x8*)(effW3 +
                        (cg * 16 + col) * 192 + (half * 3 + kh) * 32 + kgrp * 8);
            #pragma unroll
            for (int i = 0; i < 2; i++) {
                const int tile = wave + 8 * i;
                if (tile < 9) {
                    const int r = tile * 16 + col;
                    const int me = r < 136 ? r : 135;
                    #pragma unroll
                    for (int kh = 0; kh < 3; kh++) {
                        const int kk = half * 3 + kh;
                        s16x8 bfr = *(const s16x8*)&y2buf[
                            (me + 34 * (kk >> 1)) * 72 + (kk & 1) * 32 + kgrp * 8];
                        #pragma unroll
                        for (int cg = 0; cg < 4; cg++)
                            acc3[i][cg] = __builtin_amdgcn_mfma_f32_16x16x32_f16(
                                af[kh][cg], bfr, acc3[i][cg], 0, 0, 0);
                    }
                }
            }
        }
        // z3 -> y1buf rows 0..135 (y1buf dead; no reader until next barrier)
        #pragma unroll
        for (int i = 0; i < 2; i++) {
            const int tile = wave + 8 * i;
            const int r = tile * 16 + col;
            if (tile < 9 && r < 136) {
                #pragma unroll
                for (int cg = 0; cg < 4; cg++) {
                    u32x2 st;
                    st[0] = pkh(acc3[i][cg][0], acc3[i][cg][1]);
                    st[1] = pkh(acc3[i][cg][2], acc3[i][cg][3]);
                    *(u32x2*)&y1buf[r * 72 + cg * 16 + kgrp * 4] = st;
                }
            }
        }
    }
    __syncthreads();

    // ---- mix3 (packed f16) + pool ----
    if (tid < 256) {
        const int tl = tid >> 5, o0 = (tid & 31) * 2;
        const f16x2 inv2 = u2h(pkh(bnc[128 + o0], bnc[128 + o0 + 1]));
        const f16x2 sh2  = u2h(pkh(bnc[320 + o0], bnc[320 + o0 + 1]));
        const f16x2 zero = u2h(0u);
        f16x2 zk[17];
        #pragma unroll
        for (int k = 0; k < 17; k++)
            zk[k] = u2h(*(const unsigned*)&y1buf[(tl * 17 + k) * 72 + o0]);
        float ps0 = (float)rs[0], ps1 = (float)rs[1];
        #pragma unroll
        for (int v = 0; v < 17; v++) {
            f16x2 g = zero;
            #pragma unroll
            for (int e = NBR_PTR[v]; e < NBR_PTR[v + 1]; e++) {
                int k = NBR_K[e];
                g = u2h(adj_h[k * 17 + v]) * zk[k] + g;
            }
            f16x2 val = __builtin_elementwise_max(g * inv2 + sh2, zero);
            ps0 += (float)val[0];
            ps1 += (float)val[1];
        }
        *(float2*)&pr[tl * 64 + o0] = make_float2(ps0, ps1);
    }
    __syncthreads();
    if (tid < 64) {
        float s = 0.f;
        #pragma unroll
        for (int i = 0; i < 8; i++) s += pr[i * 64 + tid];
        part[((size_t)b * 256 + blockIdx.x) * 64 + tid] = s;
    }
}

// ---------------------------------------------------------------------------
// Sum 256 partials per (b,c) with 256 threads, mean, LayerNorm, FC.
// ---------------------------------------------------------------------------
__global__ __launch_bounds__(256) void finish_kernel(
    const float* __restrict__ part, const float* __restrict__ ln_s,
    const float* __restrict__ ln_b, const float* __restrict__ fc_w,
    const float* __restrict__ fc_b, float* __restrict__ out)
{
    __shared__ float red[4][64];
    __shared__ float ns[64];
    const int b = blockIdx.x;
    const int g = threadIdx.x >> 6, c = threadIdx.x & 63;
    float s = 0.f;
    for (int j = 0; j < 64; j++)
        s += part[((size_t)b * 256 + g * 64 + j) * 64 + c];
    red[g][c] = s;
    __syncthreads();
    if (threadIdx.x < 64) {
        float feat = (red[0][c] + red[1][c] + red[2][c] + red[3][c])
                   / (float)(T_DIM * K_DIM);
        float m = feat;
        #pragma unroll
        for (int off = 32; off > 0; off >>= 1) m += __shfl_down(m, off);
        m = __shfl(m, 0) / 64.f;
        float d = feat - m;
        float v = d * d;
        #pragma unroll
        for (int off = 32; off > 0; off >>= 1) v += __shfl_down(v, off);
        v = __shfl(v, 0) / 64.f;
        ns[c] = d * rsqrtf(v + 1e-5f) * ln_s[c] + ln_b[c];
    }
    __syncthreads();
    if (threadIdx.x < 10) {
        float o = fc_b[threadIdx.x];
        for (int i = 0; i < 64; i++) o += ns[i] * fc_w[i * 10 + threadIdx.x];
        out[b * 10 + threadIdx.x] = o;
    }
}

// ---------------------------------------------------------------------------
extern "C" void kernel_launch(void* const* d_in, const int* in_sizes, int n_in,
                              void* d_out, int out_size, void* d_ws, size_t ws_size,
                              hipStream_t stream)
{
    const float* kpts = (const float*)d_in[0];
    const float* adj  = (const float*)d_in[1];
    const float* gw0  = (const float*)d_in[2];
    const float* gw1  = (const float*)d_in[3];
    const float* gw2  = (const float*)d_in[4];
    const float* tcn  = (const float*)d_in[5];
    const float* bns  = (const float*)d_in[6];
    const float* bnb  = (const float*)d_in[7];
    const float* bnm  = (const float*)d_in[8];
    const float* bnv  = (const float*)d_in[9];
    const float* lns  = (const float*)d_in[10];
    const float* lnb  = (const float*)d_in[11];
    const float* fcw  = (const float*)d_in[12];
    const float* fcb  = (const float*)d_in[13];
    float* out = (float*)d_out;

    // ws: bnc | part | effT0 | effT12  (~2.1 MB total)
    float* bnc  = (float*)d_ws;
    float* part = bnc + 384;
    short* effT0  = (short*)(part + (size_t)B_DIM * 256 * 64);
    short* effT12 = effT0 + 2048;

    fold_weights_kernel<<<64, 256, 0, stream>>>(gw0, gw1, gw2, tcn,
                                                bns, bnb, bnm, bnv,
                                                effT0, effT12, bnc);

    stgcn_fused_kernel<<<dim3(T_DIM / 8, B_DIM), 512, 0, stream>>>(
        kpts, adj, effT0, effT12, effT12 + 12288, bnc, part);

    finish_kernel<<<B_DIM, 256, 0, stream>>>(part, lns, lnb, fcw, fcb, out);
}

// Round 5
// 361.317 us; speedup vs baseline: 1.4499x; 1.4499x over previous
//
#include <hip/hip_runtime.h>
#include <hip/hip_fp16.h>
#include <math.h>

#define T_DIM 2048
#define K_DIM 17
#define HID   64
#define B_DIM 32

typedef short s16x8 __attribute__((ext_vector_type(8)));
typedef unsigned u32x2 __attribute__((ext_vector_type(2)));
typedef float f32x4 __attribute__((ext_vector_type(4)));
typedef float f32x16 __attribute__((ext_vector_type(16)));
typedef _Float16 f16x2 __attribute__((ext_vector_type(2)));

// packed f32 pair -> f16 pair (1 instruction: v_cvt_pkrtz_f16_f32)
__device__ __forceinline__ unsigned pkh(float lo, float hi) {
    return __builtin_bit_cast(unsigned, __builtin_amdgcn_cvt_pkrtz(lo, hi));
}
__device__ __forceinline__ f16x2 u2h(unsigned v) {
    return __builtin_bit_cast(f16x2, v);
}
__device__ __forceinline__ unsigned h2u(f16x2 v) {
    return __builtin_bit_cast(unsigned, v);
}
__device__ __forceinline__ short f2h(float f) {          // cold path
    _Float16 h = (_Float16)f;
    return __builtin_bit_cast(short, h);
}

// COCO skeleton sparsity: column-v nonzeros of adj (incl. self).
static constexpr int NBR_PTR[18] = {0,3,6,9,11,13,17,21,24,27,29,31,34,37,40,43,45,47};
static constexpr int NBR_K[47] = {
    0,1,2,  0,1,3,  0,2,4,  1,3,  2,4,
    5,6,7,11,  5,6,8,12,  5,7,9,  6,8,10,  7,9,  8,10,
    5,11,13,  6,12,14,  11,13,15,  12,14,16,  13,15,  14,16 };
__device__ const int d_NBR_PTR[18] = {0,3,6,9,11,13,17,21,24,27,29,31,34,37,40,43,45,47};
__device__ const int d_NBR_K[47] = {
    0,1,2,  0,1,3,  0,2,4,  1,3,  2,4,
    5,6,7,11,  5,6,8,12,  5,7,9,  6,8,10,  7,9,  8,10,
    5,11,13,  6,12,14,  11,13,15,  12,14,16,  13,15,  14,16 };

// ---------------------------------------------------------------------------
// Fold GCN channel-mix into temporal conv weights (f16).
//   effT0[o][k32]  k = dt*8+cin (cin<3, dt<3), rest 0    (block1, K=32)
//   effT12[blk][o][dt*64+c]                              (blocks 2,3, K=192)
//   bnc[blk*64+o] = s/sqrt(v+eps);  bnc[192+blk*64+o] = b - m*inv
// ---------------------------------------------------------------------------
__global__ void fold_weights_kernel(
    const float* __restrict__ gw0, const float* __restrict__ gw1,
    const float* __restrict__ gw2, const float* __restrict__ tcn,
    const float* __restrict__ bns, const float* __restrict__ bnb,
    const float* __restrict__ bnm, const float* __restrict__ bnv,
    short* __restrict__ effT0, short* __restrict__ effT12,
    float* __restrict__ bnc)
{
    int tid = blockIdx.x * blockDim.x + threadIdx.x;
    int stride = gridDim.x * blockDim.x;
    for (int idx = tid; idx < 2048; idx += stride) {
        int o = idx >> 5, k = idx & 31, dt = k >> 3, cin = k & 7;
        float s = 0.f;
        if (dt < 3 && cin < 3)
            for (int m = 0; m < 64; m++)
                s += gw0[cin * 64 + m] * tcn[(o * 64 + m) * 3 + dt];
        effT0[idx] = f2h(s);
    }
    for (int idx = tid; idx < 24576; idx += stride) {
        int blk = idx / 12288;
        int r = idx - blk * 12288;
        int o = r / 192, k = r - o * 192, dt = k >> 6, c = k & 63;
        const float* gw = blk ? gw2 : gw1;
        const float* tw = tcn + (size_t)(blk + 1) * 64 * 64 * 3;
        float s = 0.f;
        for (int m = 0; m < 64; m++)
            s += gw[c * 64 + m] * tw[(o * 64 + m) * 3 + dt];
        effT12[idx] = f2h(s);
    }
    for (int i = tid; i < 192; i += stride) {
        float inv = bns[i] * rsqrtf(bnv[i] + 1e-5f);
        bnc[i] = inv;
        bnc[192 + i] = bnb[i] - bnm[i] * inv;
    }
}

// ---------------------------------------------------------------------------
// Fully fused kernel (r2 structure): premix + block1 + block2 + block3 +
// pool, all in LDS.  512 threads / 8 waves.
// GEMM1: r2's 16x16x32 mapping (wv = wave&3 channel group, wg tile split).
// GEMM2/GEMM3: 32x32x16 MFMA.  Wave w: cg = w&1 (32-ch group), rg = w>>1
// (row-tile group).  One LDS B-read (b128) feeds a 32x32 output tile -> half
// the ds_read_b128 traffic of the 16x16 form.  Weights resident: aw[12] = 48
// VGPR, loaded ONCE from global outside the MFMA loop (r3 lesson: no in-loop
// global loads, no >128-reg demand).
// LDS 72.7 KB -> 2 blocks/CU x 8 waves = 4 waves/SIMD.
// ---------------------------------------------------------------------------
__global__ __launch_bounds__(512, 4) void stgcn_fused_kernel(
    const float* __restrict__ x, const float* __restrict__ adj,
    const short* __restrict__ effT0, const short* __restrict__ effT12,
    const short* __restrict__ effW3, const float* __restrict__ bnc,
    float* __restrict__ part)
{
    __shared__ unsigned adj_h[289];                    // f16x2 broadcast pairs
    __shared__ float adj_f[289];
    __shared__ __align__(16) float xs[16 * 51];        // raw x rows t0-4..t0+11
    __shared__ __align__(16) float xtg[16 * 52];       // premixed
    __shared__ __align__(16) short y1buf[238 * 72];    // 34272 B
    __shared__ __align__(16) short y2buf[204 * 72];    // 29376 B
    float* const pr = xs;                              // pool partials alias

    const int tid = threadIdx.x;
    const int b = blockIdx.y;
    const int t0 = blockIdx.x * 8;
    const int lane = tid & 63, wave = tid >> 6;
    const int col = lane & 15, kgrp = lane >> 4;
    const int wv = wave & 3, wg = wave >> 2;           // GEMM1 mapping
    const int cg = wave & 1, rg = wave >> 1;           // GEMM2/3 mapping
    const int l31 = lane & 31, kh = lane >> 5;         // 32x32 fragment coords

    for (int i = tid; i < 289; i += 512) {
        float w = adj[i];
        adj_f[i] = w;
        adj_h[i] = pkh(w, w);
    }
    {   // coalesced stage of raw x rows t = t0-4 .. t0+11 (zero for OOB t)
        const float* src = x + ((size_t)b * T_DIM + t0 - 4) * 51;
        for (int i = tid; i < 816; i += 512) {
            const int row = i / 51;
            const int t = t0 - 4 + row;
            xs[i] = (t >= 0 && t < T_DIM) ? src[i] : 0.f;
        }
    }
    // block-1 A-frag (16x16x32): o = wv*16 + col
    s16x8 af1 = *(const s16x8*)(effT0 + (wv * 16 + col) * 32 + kgrp * 8);
    __syncthreads();

    // ---- premix: xtg[r][j*3+c] = sum_k adj[k][j] * xs[r][k*3+c] ----
    for (int i = tid; i < 272; i += 512) {
        const int r = (i * 241) >> 12;                 // i/17
        const int j = i - r * 17;
        const float* xp = &xs[r * 51];
        float a0 = 0.f, a1 = 0.f, a2 = 0.f;
        const int p0 = d_NBR_PTR[j], p1 = d_NBR_PTR[j + 1];
        for (int e = p0; e < p1; e++) {
            const int k = d_NBR_K[e];
            const float w = adj_f[k * 17 + j];
            a0 += w * xp[k * 3 + 0];
            a1 += w * xp[k * 3 + 1];
            a2 += w * xp[k * 3 + 2];
        }
        float* op = &xtg[r * 52 + j * 3];
        op[0] = a0; op[1] = a1; op[2] = a2;
    }
    __syncthreads();

    // ---- GEMM1 (r2 verbatim): 238 rows (15 tiles, wg-interleaved), K=32;
    //      epilogue BN+ReLU (+t-valid zeroing) -> y1 rows (t = t0-3..t0+10) ----
    {
        f32x4 inv4 = *(const f32x4*)&bnc[wv * 16 + kgrp * 4];
        f32x4 sh4  = *(const f32x4*)&bnc[192 + wv * 16 + kgrp * 4];
        for (int tile = wg; tile < 15; tile += 2) {
            const int r = tile * 16 + col;
            const int me = r < 238 ? r : 237;
            const int s = (me * 241) >> 12;            // me/17
            const int j = me - s * 17;
            int4 bz = {0, 0, 0, 0};
            if (kgrp < 3) {                            // dt = kgrp
                const float* xp = &xtg[(s + kgrp) * 52 + j * 3];
                bz.x = (int)pkh(xp[0], xp[1]);
                bz.y = (int)pkh(xp[2], 0.f);
            }
            s16x8 bfr = __builtin_bit_cast(s16x8, bz);
            f32x4 acc = __builtin_amdgcn_mfma_f32_16x16x32_f16(
                af1, bfr, (f32x4){0.f, 0.f, 0.f, 0.f}, 0, 0, 0);
            const int t = t0 - 3 + s;
            const bool valid = (t >= 0) && (t < T_DIM);
            if (r < 238) {
                float v0 = valid ? fmaxf(acc[0] * inv4[0] + sh4[0], 0.f) : 0.f;
                float v1 = valid ? fmaxf(acc[1] * inv4[1] + sh4[1], 0.f) : 0.f;
                float v2 = valid ? fmaxf(acc[2] * inv4[2] + sh4[2], 0.f) : 0.f;
                float v3 = valid ? fmaxf(acc[3] * inv4[3] + sh4[3], 0.f) : 0.f;
                u32x2 st; st[0] = pkh(v0, v1); st[1] = pkh(v2, v3);
                *(u32x2*)&y1buf[r * 72 + wv * 16 + kgrp * 4] = st;
            }
        }
    }
    __syncthreads();

    // ---- GEMM2: 204 rows as 7 tiles of 32 rows, 32x32x16, K=192 (12 steps).
    //      Wave: cg channel half, tiles rg and rg+4 (rg<3). ----
    {
        s16x8 aw[12];                                  // W2[cg] resident, 48 VGPR
        #pragma unroll
        for (int ks = 0; ks < 12; ks++)
            aw[ks] = *(const s16x8*)(effT12 +
                (cg * 32 + l31) * 192 + ks * 16 + kh * 8);
        f32x16 acc0 = (f32x16){0.f,0.f,0.f,0.f,0.f,0.f,0.f,0.f,
                               0.f,0.f,0.f,0.f,0.f,0.f,0.f,0.f};
        f32x16 acc1 = acc0;
        const int r0 = rg * 32 + l31;
        const int me0 = r0 < 204 ? r0 : 203;
        const int r1 = (rg + 4) * 32 + l31;
        const int me1 = r1 < 204 ? r1 : 203;
        #pragma unroll
        for (int ks = 0; ks < 12; ks++) {
            const int dt = ks >> 2, c0 = (ks & 3) * 16 + kh * 8;
            s16x8 b0 = *(const s16x8*)&y1buf[(me0 + 17 * dt) * 72 + c0];
            acc0 = __builtin_amdgcn_mfma_f32_32x32x16_f16(aw[ks], b0, acc0, 0, 0, 0);
            if (rg < 3) {
                s16x8 b1 = *(const s16x8*)&y1buf[(me1 + 17 * dt) * 72 + c0];
                acc1 = __builtin_amdgcn_mfma_f32_32x32x16_f16(aw[ks], b1, acc1, 0, 0, 0);
            }
        }
        // z2 -> y2buf.  D: n = l31 (row), m = (reg&3)+8*(reg>>2)+4*kh (ch).
        if (r0 < 204) {
            #pragma unroll
            for (int q = 0; q < 4; q++) {
                u32x2 st;
                st[0] = pkh(acc0[4 * q + 0], acc0[4 * q + 1]);
                st[1] = pkh(acc0[4 * q + 2], acc0[4 * q + 3]);
                *(u32x2*)&y2buf[r0 * 72 + cg * 32 + q * 8 + kh * 4] = st;
            }
        }
        if (rg < 3 && r1 < 204) {
            #pragma unroll
            for (int q = 0; q < 4; q++) {
                u32x2 st;
                st[0] = pkh(acc1[4 * q + 0], acc1[4 * q + 1]);
                st[1] = pkh(acc1[4 * q + 2], acc1[4 * q + 3]);
                *(u32x2*)&y2buf[r1 * 72 + cg * 32 + q * 8 + kh * 4] = st;
            }
        }
    }
    __syncthreads();

    // ---- mix2 (packed f16) in-place on y2buf + y1 residual + invalid-t
    //      zeroing.  Each item (tl,o0) reads exactly the cells it writes. ----
    if (tid < 384) {
        const f16x2 zero = u2h(0u);
        const int tl = tid >> 5, o0 = (tid & 31) * 2;
        const f16x2 inv2 = u2h(pkh(bnc[64 + o0], bnc[64 + o0 + 1]));
        const f16x2 sh2  = u2h(pkh(bnc[256 + o0], bnc[256 + o0 + 1]));
        f16x2 zk[17];
        #pragma unroll
        for (int k = 0; k < 17; k++)
            zk[k] = u2h(*(const unsigned*)&y2buf[(tl * 17 + k) * 72 + o0]);
        const int t = t0 - 2 + tl;
        const bool valid = (t >= 0) && (t < T_DIM);
        #pragma unroll
        for (int v = 0; v < 17; v++) {
            f16x2 g = zero;
            #pragma unroll
            for (int e = NBR_PTR[v]; e < NBR_PTR[v + 1]; e++) {
                int k = NBR_K[e];
                g = u2h(adj_h[k * 17 + v]) * zk[k] + g;
            }
            f16x2 val = __builtin_elementwise_max(g * inv2 + sh2, zero);
            val = val + u2h(*(const unsigned*)&y1buf[
                ((tl + 1) * 17 + v) * 72 + o0]);
            *(unsigned*)&y2buf[(tl * 17 + v) * 72 + o0] =
                valid ? h2u(val) : 0u;
        }
    }
    __syncthreads();

    // ---- residual/pool pre-sum over y2 rows t0..t0+7 ----
    f16x2 rs = u2h(0u);
    if (tid < 256) {
        const int tl = tid >> 5, o0 = (tid & 31) * 2;
        #pragma unroll
        for (int v = 0; v < 17; v++)
            rs = rs + u2h(*(const unsigned*)&y2buf[((tl + 2) * 17 + v) * 72 + o0]);
    }

    // ---- GEMM3: 136 rows as 5 tiles of 32, 32x32x16, K=192, DIL=2.
    //      Wave: cg channel half, tile rg (+ tile 4 for rg==0). ----
    {
        s16x8 aw3[12];                                 // W3[cg] resident
        #pragma unroll
        for (int ks = 0; ks < 12; ks++)
            aw3[ks] = *(const s16x8*)(effW3 +
                (cg * 32 + l31) * 192 + ks * 16 + kh * 8);
        f32x16 acc0 = (f32x16){0.f,0.f,0.f,0.f,0.f,0.f,0.f,0.f,
                               0.f,0.f,0.f,0.f,0.f,0.f,0.f,0.f};
        f32x16 acc1 = acc0;
        const int r0 = rg * 32 + l31;
        const int me0 = r0 < 136 ? r0 : 135;
        const int r1 = 128 + l31;                      // tile 4 (rg==0 only)
        const int me1 = r1 < 136 ? r1 : 135;
        #pragma unroll
        for (int ks = 0; ks < 12; ks++) {
            const int dt = ks >> 2, c0 = (ks & 3) * 16 + kh * 8;
            s16x8 b0 = *(const s16x8*)&y2buf[(me0 + 34 * dt) * 72 + c0];
            acc0 = __builtin_amdgcn_mfma_f32_32x32x16_f16(aw3[ks], b0, acc0, 0, 0, 0);
            if (rg == 0) {
                s16x8 b1 = *(const s16x8*)&y2buf[(me1 + 34 * dt) * 72 + c0];
                acc1 = __builtin_amdgcn_mfma_f32_32x32x16_f16(aw3[ks], b1, acc1, 0, 0, 0);
            }
        }
        // z3 -> y1buf rows 0..135 (y1buf dead after mix2)
        if (r0 < 136) {
            #pragma unroll
            for (int q = 0; q < 4; q++) {
                u32x2 st;
                st[0] = pkh(acc0[4 * q + 0], acc0[4 * q + 1]);
                st[1] = pkh(acc0[4 * q + 2], acc0[4 * q + 3]);
                *(u32x2*)&y1buf[r0 * 72 + cg * 32 + q * 8 + kh * 4] = st;
            }
        }
        if (rg == 0 && r1 < 136) {
            #pragma unroll
            for (int q = 0; q < 4; q++) {
                u32x2 st;
                st[0] = pkh(acc1[4 * q + 0], acc1[4 * q + 1]);
                st[1] = pkh(acc1[4 * q + 2], acc1[4 * q + 3]);
                *(u32x2*)&y1buf[r1 * 72 + cg * 32 + q * 8 + kh * 4] = st;
            }
        }
    }
    __syncthreads();

    // ---- mix3 (packed f16) + pool ----
    if (tid < 256) {
        const int tl = tid >> 5, o0 = (tid & 31) * 2;
        const f16x2 inv2 = u2h(pkh(bnc[128 + o0], bnc[128 + o0 + 1]));
        const f16x2 sh2  = u2h(pkh(bnc[320 + o0], bnc[320 + o0 + 1]));
        const f16x2 zero = u2h(0u);
        f16x2 zk[17];
        #pragma unroll
        for (int k = 0; k < 17; k++)
            zk[k] = u2h(*(const unsigned*)&y1buf[(tl * 17 + k) * 72 + o0]);
        float ps0 = (float)rs[0], ps1 = (float)rs[1];
        #pragma unroll
        for (int v = 0; v < 17; v++) {
            f16x2 g = zero;
            #pragma unroll
            for (int e = NBR_PTR[v]; e < NBR_PTR[v + 1]; e++) {
                int k = NBR_K[e];
                g = u2h(adj_h[k * 17 + v]) * zk[k] + g;
            }
            f16x2 val = __builtin_elementwise_max(g * inv2 + sh2, zero);
            ps0 += (float)val[0];
            ps1 += (float)val[1];
        }
        *(float2*)&pr[tl * 64 + o0] = make_float2(ps0, ps1);
    }
    __syncthreads();
    if (tid < 64) {
        float s = 0.f;
        #pragma unroll
        for (int i = 0; i < 8; i++) s += pr[i * 64 + tid];
        part[((size_t)b * 256 + blockIdx.x) * 64 + tid] = s;
    }
}

// ---------------------------------------------------------------------------
// Sum 256 partials per (b,c) with 256 threads, mean, LayerNorm, FC.
// ---------------------------------------------------------------------------
__global__ __launch_bounds__(256) void finish_kernel(
    const float* __restrict__ part, const float* __restrict__ ln_s,
    const float* __restrict__ ln_b, const float* __restrict__ fc_w,
    const float* __restrict__ fc_b, float* __restrict__ out)
{
    __shared__ float red[4][64];
    __shared__ float ns[64];
    const int b = blockIdx.x;
    const int g = threadIdx.x >> 6, c = threadIdx.x & 63;
    float s = 0.f;
    for (int j = 0; j < 64; j++)
        s += part[((size_t)b * 256 + g * 64 + j) * 64 + c];
    red[g][c] = s;
    __syncthreads();
    if (threadIdx.x < 64) {
        float feat = (red[0][c] + red[1][c] + red[2][c] + red[3][c])
                   / (float)(T_DIM * K_DIM);
        float m = feat;
        #pragma unroll
        for (int off = 32; off > 0; off >>= 1) m += __shfl_down(m, off);
        m = __shfl(m, 0) / 64.f;
        float d = feat - m;
        float v = d * d;
        #pragma unroll
        for (int off = 32; off > 0; off >>= 1) v += __shfl_down(v, off);
        v = __shfl(v, 0) / 64.f;
        ns[c] = d * rsqrtf(v + 1e-5f) * ln_s[c] + ln_b[c];
    }
    __syncthreads();
    if (threadIdx.x < 10) {
        float o = fc_b[threadIdx.x];
        for (int i = 0; i < 64; i++) o += ns[i] * fc_w[i * 10 + threadIdx.x];
        out[b * 10 + threadIdx.x] = o;
    }
}

// ---------------------------------------------------------------------------
extern "C" void kernel_launch(void* const* d_in, const int* in_sizes, int n_in,
                              void* d_out, int out_size, void* d_ws, size_t ws_size,
                              hipStream_t stream)
{
    const float* kpts = (const float*)d_in[0];
    const float* adj  = (const float*)d_in[1];
    const float* gw0  = (const float*)d_in[2];
    const float* gw1  = (const float*)d_in[3];
    const float* gw2  = (const float*)d_in[4];
    const float* tcn  = (const float*)d_in[5];
    const float* bns  = (const float*)d_in[6];
    const float* bnb  = (const float*)d_in[7];
    const float* bnm  = (const float*)d_in[8];
    const float* bnv  = (const float*)d_in[9];
    const float* lns  = (const float*)d_in[10];
    const float* lnb  = (const float*)d_in[11];
    const float* fcw  = (const float*)d_in[12];
    const float* fcb  = (const float*)d_in[13];
    float* out = (float*)d_out;

    // ws: bnc | part | effT0 | effT12  (~2.1 MB total)
    float* bnc  = (float*)d_ws;
    float* part = bnc + 384;
    short* effT0  = (short*)(part + (size_t)B_DIM * 256 * 64);
    short* effT12 = effT0 + 2048;

    fold_weights_kernel<<<64, 256, 0, stream>>>(gw0, gw1, gw2, tcn,
                                                bns, bnb, bnm, bnv,
                                                effT0, effT12, bnc);

    stgcn_fused_kernel<<<dim3(T_DIM / 8, B_DIM), 512, 0, stream>>>(
        kpts, adj, effT0, effT12, effT12 + 12288, bnc, part);

    finish_kernel<<<B_DIM, 256, 0, stream>>>(part, lns, lnb, fcw, fcb, out);
}

// Round 8
// 355.062 us; speedup vs baseline: 1.4755x; 1.0176x over previous
//
#include <hip/hip_runtime.h>
#include <hip/hip_fp16.h>
#include <math.h>

#define T_DIM 2048
#define K_DIM 17
#define HID   64
#define B_DIM 32

typedef short s16x8 __attribute__((ext_vector_type(8)));
typedef unsigned u32x2 __attribute__((ext_vector_type(2)));
typedef float f32x4 __attribute__((ext_vector_type(4)));
typedef float f32x16 __attribute__((ext_vector_type(16)));
typedef _Float16 f16x2 __attribute__((ext_vector_type(2)));

// packed f32 pair -> f16 pair (1 instruction: v_cvt_pkrtz_f16_f32)
__device__ __forceinline__ unsigned pkh(float lo, float hi) {
    return __builtin_bit_cast(unsigned, __builtin_amdgcn_cvt_pkrtz(lo, hi));
}
__device__ __forceinline__ f16x2 u2h(unsigned v) {
    return __builtin_bit_cast(f16x2, v);
}
__device__ __forceinline__ unsigned h2u(f16x2 v) {
    return __builtin_bit_cast(unsigned, v);
}
__device__ __forceinline__ short f2h(float f) {          // cold path
    _Float16 h = (_Float16)f;
    return __builtin_bit_cast(short, h);
}

// COCO skeleton sparsity: column-v nonzeros of adj (incl. self).
static constexpr int NBR_PTR[18] = {0,3,6,9,11,13,17,21,24,27,29,31,34,37,40,43,45,47};
static constexpr int NBR_K[47] = {
    0,1,2,  0,1,3,  0,2,4,  1,3,  2,4,
    5,6,7,11,  5,6,8,12,  5,7,9,  6,8,10,  7,9,  8,10,
    5,11,13,  6,12,14,  11,13,15,  12,14,16,  13,15,  14,16 };
__device__ const int d_NBR_PTR[18] = {0,3,6,9,11,13,17,21,24,27,29,31,34,37,40,43,45,47};
__device__ const int d_NBR_K[47] = {
    0,1,2,  0,1,3,  0,2,4,  1,3,  2,4,
    5,6,7,11,  5,6,8,12,  5,7,9,  6,8,10,  7,9,  8,10,
    5,11,13,  6,12,14,  11,13,15,  12,14,16,  13,15,  14,16 };

// ---------------------------------------------------------------------------
// Fold GCN channel-mix into temporal conv weights (f16).
//   effT0[o][k32]  k = dt*8+cin (cin<3, dt<3), rest 0    (block1, K=32)
//   effT12[blk][o][dt*64+c]                              (blocks 2,3, K=192)
//   bnc[blk*64+o] = s/sqrt(v+eps);  bnc[192+blk*64+o] = b - m*inv
// ---------------------------------------------------------------------------
__global__ void fold_weights_kernel(
    const float* __restrict__ gw0, const float* __restrict__ gw1,
    const float* __restrict__ gw2, const float* __restrict__ tcn,
    const float* __restrict__ bns, const float* __restrict__ bnb,
    const float* __restrict__ bnm, const float* __restrict__ bnv,
    short* __restrict__ effT0, short* __restrict__ effT12,
    float* __restrict__ bnc)
{
    int tid = blockIdx.x * blockDim.x + threadIdx.x;
    int stride = gridDim.x * blockDim.x;
    for (int idx = tid; idx < 2048; idx += stride) {
        int o = idx >> 5, k = idx & 31, dt = k >> 3, cin = k & 7;
        float s = 0.f;
        if (dt < 3 && cin < 3)
            for (int m = 0; m < 64; m++)
                s += gw0[cin * 64 + m] * tcn[(o * 64 + m) * 3 + dt];
        effT0[idx] = f2h(s);
    }
    for (int idx = tid; idx < 24576; idx += stride) {
        int blk = idx / 12288;
        int r = idx - blk * 12288;
        int o = r / 192, k = r - o * 192, dt = k >> 6, c = k & 63;
        const float* gw = blk ? gw2 : gw1;
        const float* tw = tcn + (size_t)(blk + 1) * 64 * 64 * 3;
        float s = 0.f;
        for (int m = 0; m < 64; m++)
            s += gw[c * 64 + m] * tw[(o * 64 + m) * 3 + dt];
        effT12[idx] = f2h(s);
    }
    for (int i = tid; i < 192; i += stride) {
        float inv = bns[i] * rsqrtf(bnv[i] + 1e-5f);
        bnc[i] = inv;
        bnc[192 + i] = bnb[i] - bnm[i] * inv;
    }
}

// ---------------------------------------------------------------------------
// Fully fused kernel: premix + block1 + block2 + block3 + pool, all in LDS.
// 512 threads / 8 waves.
// GEMM1: 16x16x32 (wv = wave&3 channel group, wg tile split).
// GEMM2/GEMM3: 32x32x16.  Wave w: cg = w&1 (32-ch group), rg = w>>1
// (row-tile group).  One LDS B-read (b128) feeds a 32x32 output tile.
// A-weights loaded per K-HALF: aw[6] = 24 VGPR (r5 used aw[12] = 48 VGPR,
// which hit the 128-reg unified cap -> compiler pushed aw to AGPR with
// shuttle moves on the MFMA critical path; VGPR_Count stuck at 52).
// Unified demand now ~90 < 128.
// LDS 72.7 KB -> 2 blocks/CU x 8 waves = 4 waves/SIMD.
// ---------------------------------------------------------------------------
__global__ __launch_bounds__(512, 4) void stgcn_fused_kernel(
    const float* __restrict__ x, const float* __restrict__ adj,
    const short* __restrict__ effT0, const short* __restrict__ effT12,
    const short* __restrict__ effW3, const float* __restrict__ bnc,
    float* __restrict__ part)
{
    __shared__ unsigned adj_h[289];                    // f16x2 broadcast pairs
    __shared__ float adj_f[289];
    __shared__ __align__(16) float xs[16 * 51];        // raw x rows t0-4..t0+11
    __shared__ __align__(16) float xtg[16 * 52];       // premixed
    __shared__ __align__(16) short y1buf[238 * 72];    // 34272 B
    __shared__ __align__(16) short y2buf[204 * 72];    // 29376 B
    float* const pr = xs;                              // pool partials alias

    const int tid = threadIdx.x;
    const int b = blockIdx.y;
    const int t0 = blockIdx.x * 8;
    const int lane = tid & 63, wave = tid >> 6;
    const int col = lane & 15, kgrp = lane >> 4;
    const int wv = wave & 3, wg = wave >> 2;           // GEMM1 mapping
    const int cg = wave & 1, rg = wave >> 1;           // GEMM2/3 mapping
    const int l31 = lane & 31, kh = lane >> 5;         // 32x32 fragment coords

    for (int i = tid; i < 289; i += 512) {
        float w = adj[i];
        adj_f[i] = w;
        adj_h[i] = pkh(w, w);
    }
    {   // coalesced stage of raw x rows t = t0-4 .. t0+11 (zero for OOB t)
        const float* src = x + ((size_t)b * T_DIM + t0 - 4) * 51;
        for (int i = tid; i < 816; i += 512) {
            const int row = i / 51;
            const int t = t0 - 4 + row;
            xs[i] = (t >= 0 && t < T_DIM) ? src[i] : 0.f;
        }
    }
    // block-1 A-frag (16x16x32): o = wv*16 + col
    s16x8 af1 = *(const s16x8*)(effT0 + (wv * 16 + col) * 32 + kgrp * 8);
    __syncthreads();

    // ---- premix: xtg[r][j*3+c] = sum_k adj[k][j] * xs[r][k*3+c] ----
    for (int i = tid; i < 272; i += 512) {
        const int r = (i * 241) >> 12;                 // i/17
        const int j = i - r * 17;
        const float* xp = &xs[r * 51];
        float a0 = 0.f, a1 = 0.f, a2 = 0.f;
        const int p0 = d_NBR_PTR[j], p1 = d_NBR_PTR[j + 1];
        for (int e = p0; e < p1; e++) {
            const int k = d_NBR_K[e];
            const float w = adj_f[k * 17 + j];
            a0 += w * xp[k * 3 + 0];
            a1 += w * xp[k * 3 + 1];
            a2 += w * xp[k * 3 + 2];
        }
        float* op = &xtg[r * 52 + j * 3];
        op[0] = a0; op[1] = a1; op[2] = a2;
    }
    __syncthreads();

    // ---- GEMM1: 238 rows (15 tiles, wg-interleaved), K=32; epilogue
    //      BN+ReLU (+t-valid zeroing) -> y1 rows (t = t0-3..t0+10) ----
    {
        f32x4 inv4 = *(const f32x4*)&bnc[wv * 16 + kgrp * 4];
        f32x4 sh4  = *(const f32x4*)&bnc[192 + wv * 16 + kgrp * 4];
        for (int tile = wg; tile < 15; tile += 2) {
            const int r = tile * 16 + col;
            const int me = r < 238 ? r : 237;
            const int s = (me * 241) >> 12;            // me/17
            const int j = me - s * 17;
            int4 bz = {0, 0, 0, 0};
            if (kgrp < 3) {                            // dt = kgrp
                const float* xp = &xtg[(s + kgrp) * 52 + j * 3];
                bz.x = (int)pkh(xp[0], xp[1]);
                bz.y = (int)pkh(xp[2], 0.f);
            }
            s16x8 bfr = __builtin_bit_cast(s16x8, bz);
            f32x4 acc = __builtin_amdgcn_mfma_f32_16x16x32_f16(
                af1, bfr, (f32x4){0.f, 0.f, 0.f, 0.f}, 0, 0, 0);
            const int t = t0 - 3 + s;
            const bool valid = (t >= 0) && (t < T_DIM);
            if (r < 238) {
                float v0 = valid ? fmaxf(acc[0] * inv4[0] + sh4[0], 0.f) : 0.f;
                float v1 = valid ? fmaxf(acc[1] * inv4[1] + sh4[1], 0.f) : 0.f;
                float v2 = valid ? fmaxf(acc[2] * inv4[2] + sh4[2], 0.f) : 0.f;
                float v3 = valid ? fmaxf(acc[3] * inv4[3] + sh4[3], 0.f) : 0.f;
                u32x2 st; st[0] = pkh(v0, v1); st[1] = pkh(v2, v3);
                *(u32x2*)&y1buf[r * 72 + wv * 16 + kgrp * 4] = st;
            }
        }
    }
    __syncthreads();

    // ---- GEMM2: 204 rows as 7 tiles of 32 rows, 32x32x16, K=192 (12 steps
    //      in 2 halves of 6).  Wave: cg channel half, tiles rg, rg+4 (rg<3).
    {
        f32x16 acc0 = (f32x16){0.f,0.f,0.f,0.f,0.f,0.f,0.f,0.f,
                               0.f,0.f,0.f,0.f,0.f,0.f,0.f,0.f};
        f32x16 acc1 = acc0;
        const int r0 = rg * 32 + l31;
        const int me0 = r0 < 204 ? r0 : 203;
        const int r1 = (rg + 4) * 32 + l31;
        const int me1 = r1 < 204 ? r1 : 203;
        #pragma unroll
        for (int half = 0; half < 2; half++) {
            s16x8 aw[6];                               // 24 VGPR per half
            #pragma unroll
            for (int kl = 0; kl < 6; kl++)
                aw[kl] = *(const s16x8*)(effT12 +
                    (cg * 32 + l31) * 192 + (half * 6 + kl) * 16 + kh * 8);
            #pragma unroll
            for (int kl = 0; kl < 6; kl++) {
                const int ks = half * 6 + kl;
                const int dt = ks >> 2, c0 = (ks & 3) * 16 + kh * 8;
                s16x8 b0 = *(const s16x8*)&y1buf[(me0 + 17 * dt) * 72 + c0];
                acc0 = __builtin_amdgcn_mfma_f32_32x32x16_f16(aw[kl], b0, acc0, 0, 0, 0);
                if (rg < 3) {
                    s16x8 b1 = *(const s16x8*)&y1buf[(me1 + 17 * dt) * 72 + c0];
                    acc1 = __builtin_amdgcn_mfma_f32_32x32x16_f16(aw[kl], b1, acc1, 0, 0, 0);
                }
            }
        }
        // z2 -> y2buf.  D: n = l31 (row), m = (reg&3)+8*(reg>>2)+4*kh (ch).
        if (r0 < 204) {
            #pragma unroll
            for (int q = 0; q < 4; q++) {
                u32x2 st;
                st[0] = pkh(acc0[4 * q + 0], acc0[4 * q + 1]);
                st[1] = pkh(acc0[4 * q + 2], acc0[4 * q + 3]);
                *(u32x2*)&y2buf[r0 * 72 + cg * 32 + q * 8 + kh * 4] = st;
            }
        }
        if (rg < 3 && r1 < 204) {
            #pragma unroll
            for (int q = 0; q < 4; q++) {
                u32x2 st;
                st[0] = pkh(acc1[4 * q + 0], acc1[4 * q + 1]);
                st[1] = pkh(acc1[4 * q + 2], acc1[4 * q + 3]);
                *(u32x2*)&y2buf[r1 * 72 + cg * 32 + q * 8 + kh * 4] = st;
            }
        }
    }
    __syncthreads();

    // ---- mix2 (packed f16) in-place on y2buf + y1 residual + invalid-t
    //      zeroing.  Each item (tl,o0) reads exactly the cells it writes. ----
    if (tid < 384) {
        const f16x2 zero = u2h(0u);
        const int tl = tid >> 5, o0 = (tid & 31) * 2;
        const f16x2 inv2 = u2h(pkh(bnc[64 + o0], bnc[64 + o0 + 1]));
        const f16x2 sh2  = u2h(pkh(bnc[256 + o0], bnc[256 + o0 + 1]));
        f16x2 zk[17];
        #pragma unroll
        for (int k = 0; k < 17; k++)
            zk[k] = u2h(*(const unsigned*)&y2buf[(tl * 17 + k) * 72 + o0]);
        const int t = t0 - 2 + tl;
        const bool valid = (t >= 0) && (t < T_DIM);
        #pragma unroll
        for (int v = 0; v < 17; v++) {
            f16x2 g = zero;
            #pragma unroll
            for (int e = NBR_PTR[v]; e < NBR_PTR[v + 1]; e++) {
                int k = NBR_K[e];
                g = u2h(adj_h[k * 17 + v]) * zk[k] + g;
            }
            f16x2 val = __builtin_elementwise_max(g * inv2 + sh2, zero);
            val = val + u2h(*(const unsigned*)&y1buf[
                ((tl + 1) * 17 + v) * 72 + o0]);
            *(unsigned*)&y2buf[(tl * 17 + v) * 72 + o0] =
                valid ? h2u(val) : 0u;
        }
    }
    __syncthreads();

    // ---- residual/pool pre-sum over y2 rows t0..t0+7 ----
    f16x2 rs = u2h(0u);
    if (tid < 256) {
        const int tl = tid >> 5, o0 = (tid & 31) * 2;
        #pragma unroll
        for (int v = 0; v < 17; v++)
            rs = rs + u2h(*(const unsigned*)&y2buf[((tl + 2) * 17 + v) * 72 + o0]);
    }

    // ---- GEMM3: 136 rows as 5 tiles of 32, 32x32x16, K=192 (2 halves),
    //      DIL=2.  Wave: cg channel half, tile rg (+ tile 4 for rg==0). ----
    {
        f32x16 acc0 = (f32x16){0.f,0.f,0.f,0.f,0.f,0.f,0.f,0.f,
                               0.f,0.f,0.f,0.f,0.f,0.f,0.f,0.f};
        f32x16 acc1 = acc0;
        const int r0 = rg * 32 + l31;
        const int me0 = r0 < 136 ? r0 : 135;
        const int r1 = 128 + l31;                      // tile 4 (rg==0 only)
        const int me1 = r1 < 136 ? r1 : 135;
        #pragma unroll
        for (int half = 0; half < 2; half++) {
            s16x8 aw[6];                               // 24 VGPR per half
            #pragma unroll
            for (int kl = 0; kl < 6; kl++)
                aw[kl] = *(const s16x8*)(effW3 +
                    (cg * 32 + l31) * 192 + (half * 6 + kl) * 16 + kh * 8);
            #pragma unroll
            for (int kl = 0; kl < 6; kl++) {
                const int ks = half * 6 + kl;
                const int dt = ks >> 2, c0 = (ks & 3) * 16 + kh * 8;
                s16x8 b0 = *(const s16x8*)&y2buf[(me0 + 34 * dt) * 72 + c0];
                acc0 = __builtin_amdgcn_mfma_f32_32x32x16_f16(aw[kl], b0, acc0, 0, 0, 0);
                if (rg == 0) {
                    s16x8 b1 = *(const s16x8*)&y2buf[(me1 + 34 * dt) * 72 + c0];
                    acc1 = __builtin_amdgcn_mfma_f32_32x32x16_f16(aw[kl], b1, acc1, 0, 0, 0);
                }
            }
        }
        // z3 -> y1buf rows 0..135 (y1buf dead after mix2)
        if (r0 < 136) {
            #pragma unroll
            for (int q = 0; q < 4; q++) {
                u32x2 st;
                st[0] = pkh(acc0[4 * q + 0], acc0[4 * q + 1]);
                st[1] = pkh(acc0[4 * q + 2], acc0[4 * q + 3]);
                *(u32x2*)&y1buf[r0 * 72 + cg * 32 + q * 8 + kh * 4] = st;
            }
        }
        if (rg == 0 && r1 < 136) {
            #pragma unroll
            for (int q = 0; q < 4; q++) {
                u32x2 st;
                st[0] = pkh(acc1[4 * q + 0], acc1[4 * q + 1]);
                st[1] = pkh(acc1[4 * q + 2], acc1[4 * q + 3]);
                *(u32x2*)&y1buf[r1 * 72 + cg * 32 + q * 8 + kh * 4] = st;
            }
        }
    }
    __syncthreads();

    // ---- mix3 (packed f16) + pool ----
    if (tid < 256) {
        const int tl = tid >> 5, o0 = (tid & 31) * 2;
        const f16x2 inv2 = u2h(pkh(bnc[128 + o0], bnc[128 + o0 + 1]));
        const f16x2 sh2  = u2h(pkh(bnc[320 + o0], bnc[320 + o0 + 1]));
        const f16x2 zero = u2h(0u);
        f16x2 zk[17];
        #pragma unroll
        for (int k = 0; k < 17; k++)
            zk[k] = u2h(*(const unsigned*)&y1buf[(tl * 17 + k) * 72 + o0]);
        float ps0 = (float)rs[0], ps1 = (float)rs[1];
        #pragma unroll
        for (int v = 0; v < 17; v++) {
            f16x2 g = zero;
            #pragma unroll
            for (int e = NBR_PTR[v]; e < NBR_PTR[v + 1]; e++) {
                int k = NBR_K[e];
                g = u2h(adj_h[k * 17 + v]) * zk[k] + g;
            }
            f16x2 val = __builtin_elementwise_max(g * inv2 + sh2, zero);
            ps0 += (float)val[0];
            ps1 += (float)val[1];
        }
        *(float2*)&pr[tl * 64 + o0] = make_float2(ps0, ps1);
    }
    __syncthreads();
    if (tid < 64) {
        float s = 0.f;
        #pragma unroll
        for (int i = 0; i < 8; i++) s += pr[i * 64 + tid];
        part[((size_t)b * 256 + blockIdx.x) * 64 + tid] = s;
    }
}

// ---------------------------------------------------------------------------
// Sum 256 partials per (b,c) with 256 threads, mean, LayerNorm, FC.
// ---------------------------------------------------------------------------
__global__ __launch_bounds__(256) void finish_kernel(
    const float* __restrict__ part, const float* __restrict__ ln_s,
    const float* __restrict__ ln_b, const float* __restrict__ fc_w,
    const float* __restrict__ fc_b, float* __restrict__ out)
{
    __shared__ float red[4][64];
    __shared__ float ns[64];
    const int b = blockIdx.x;
    const int g = threadIdx.x >> 6, c = threadIdx.x & 63;
    float s = 0.f;
    for (int j = 0; j < 64; j++)
        s += part[((size_t)b * 256 + g * 64 + j) * 64 + c];
    red[g][c] = s;
    __syncthreads();
    if (threadIdx.x < 64) {
        float feat = (red[0][c] + red[1][c] + red[2][c] + red[3][c])
                   / (float)(T_DIM * K_DIM);
        float m = feat;
        #pragma unroll
        for (int off = 32; off > 0; off >>= 1) m += __shfl_down(m, off);
        m = __shfl(m, 0) / 64.f;
        float d = feat - m;
        float v = d * d;
        #pragma unroll
        for (int off = 32; off > 0; off >>= 1) v += __shfl_down(v, off);
        v = __shfl(v, 0) / 64.f;
        ns[c] = d * rsqrtf(v + 1e-5f) * ln_s[c] + ln_b[c];
    }
    __syncthreads();
    if (threadIdx.x < 10) {
        float o = fc_b[threadIdx.x];
        for (int i = 0; i < 64; i++) o += ns[i] * fc_w[i * 10 + threadIdx.x];
        out[b * 10 + threadIdx.x] = o;
    }
}

// ---------------------------------------------------------------------------
extern "C" void kernel_launch(void* const* d_in, const int* in_sizes, int n_in,
                              void* d_out, int out_size, void* d_ws, size_t ws_size,
                              hipStream_t stream)
{
    const float* kpts = (const float*)d_in[0];
    const float* adj  = (const float*)d_in[1];
    const float* gw0  = (const float*)d_in[2];
    const float* gw1  = (const float*)d_in[3];
    const float* gw2  = (const float*)d_in[4];
    const float* tcn  = (const float*)d_in[5];
    const float* bns  = (const float*)d_in[6];
    const float* bnb  = (const float*)d_in[7];
    const float* bnm  = (const float*)d_in[8];
    const float* bnv  = (const float*)d_in[9];
    const float* lns  = (const float*)d_in[10];
    const float* lnb  = (const float*)d_in[11];
    const float* fcw  = (const float*)d_in[12];
    const float* fcb  = (const float*)d_in[13];
    float* out = (float*)d_out;

    // ws: bnc | part | effT0 | effT12  (~2.1 MB total)
    float* bnc  = (float*)d_ws;
    float* part = bnc + 384;
    short* effT0  = (short*)(part + (size_t)B_DIM * 256 * 64);
    short* effT12 = effT0 + 2048;

    fold_weights_kernel<<<64, 256, 0, stream>>>(gw0, gw1, gw2, tcn,
                                                bns, bnb, bnm, bnv,
                                                effT0, effT12, bnc);

    stgcn_fused_kernel<<<dim3(T_DIM / 8, B_DIM), 512, 0, stream>>>(
        kpts, adj, effT0, effT12, effT12 + 12288, bnc, part);

    finish_kernel<<<B_DIM, 256, 0, stream>>>(part, lns, lnb, fcw, fcb, out);
}

// Round 12
// 241.763 us; speedup vs baseline: 2.1669x; 1.4686x over previous
//
#include <hip/hip_runtime.h>
#include <hip/hip_fp16.h>
#include <math.h>

#define T_DIM 2048
#define TP_DIM 2052                  // padded t rows: tp = t + 2, 2 pad each side
#define K_DIM 17
#define HID   64
#define B_DIM 32

typedef short s16x8 __attribute__((ext_vector_type(8)));
typedef unsigned u32x2 __attribute__((ext_vector_type(2)));
typedef float f32x4 __attribute__((ext_vector_type(4)));
typedef _Float16 f16x2 __attribute__((ext_vector_type(2)));

// packed f32 pair -> f16 pair (1 instruction: v_cvt_pkrtz_f16_f32)
__device__ __forceinline__ unsigned pkh(float lo, float hi) {
    return __builtin_bit_cast(unsigned, __builtin_amdgcn_cvt_pkrtz(lo, hi));
}
__device__ __forceinline__ f16x2 u2h(unsigned v) {
    return __builtin_bit_cast(f16x2, v);
}
__device__ __forceinline__ unsigned h2u(f16x2 v) {
    return __builtin_bit_cast(unsigned, v);
}
__device__ __forceinline__ short f2h(float f) {          // cold path
    _Float16 h = (_Float16)f;
    return __builtin_bit_cast(short, h);
}

// COCO skeleton sparsity: column-v nonzeros of adj (incl. self).
static constexpr int NBR_PTR[18] = {0,3,6,9,11,13,17,21,24,27,29,31,34,37,40,43,45,47};
static constexpr int NBR_K[47] = {
    0,1,2,  0,1,3,  0,2,4,  1,3,  2,4,
    5,6,7,11,  5,6,8,12,  5,7,9,  6,8,10,  7,9,  8,10,
    5,11,13,  6,12,14,  11,13,15,  12,14,16,  13,15,  14,16 };
__device__ const int d_NBR_PTR[18] = {0,3,6,9,11,13,17,21,24,27,29,31,34,37,40,43,45,47};
__device__ const int d_NBR_K[47] = {
    0,1,2,  0,1,3,  0,2,4,  1,3,  2,4,
    5,6,7,11,  5,6,8,12,  5,7,9,  6,8,10,  7,9,  8,10,
    5,11,13,  6,12,14,  11,13,15,  12,14,16,  13,15,  14,16 };

// ---------------------------------------------------------------------------
// Fold GCN channel-mix into temporal conv weights (f16) — LDS-staged rewrite.
// The old version issued ~1.7M uncoalesced global loads (64-iter scalar dots
// with stride-3 / stride-64 patterns) and cost ~50 us, hidden below top-k.
// New: 9 blocks.  Blocks 0..7: (blk = bid>>2, o-quarter = bid&3) stage
// gw transposed (+1 pad, conflict-free reads) and a CONTIGUOUS tcn slice in
// LDS via coalesced loads, then each thread computes 12 outputs from LDS.
// Block 8: effT0 (tcn block 0 staged, gw0 transposed) + bnc.
// Accumulation order per output (m ascending, f32) identical to original.
//   effT0[o][k32]  k = dt*8+cin (cin<3, dt<3), rest 0    (block1, K=32)
//   effT12[blk][o][dt*64+c]                              (blocks 2,3, K=192)
//   bnc[blk*64+o] = s/sqrt(v+eps);  bnc[192+blk*64+o] = b - m*inv
// ---------------------------------------------------------------------------
__global__ __launch_bounds__(256) void fold_weights_kernel(
    const float* __restrict__ gw0, const float* __restrict__ gw1,
    const float* __restrict__ gw2, const float* __restrict__ tcn,
    const float* __restrict__ bns, const float* __restrict__ bnb,
    const float* __restrict__ bnm, const float* __restrict__ bnv,
    short* __restrict__ effT0, short* __restrict__ effT12,
    float* __restrict__ bnc)
{
    __shared__ float lds[12480];     // blocks 0-7: gwT[4160] + tws[3072]; blk8: tc0[12288]
    __shared__ float g0T[256];
    const int tid = threadIdx.x;
    const int bid = blockIdx.x;

    if (bid < 8) {
        const int blk = bid >> 2, oq = bid & 3;      // o in [oq*16, oq*16+16)
        float* gwT = lds;                            // [m][c] padded 65
        float* tws = lds + 4160;                     // tcn slice, 3072 floats
        const float* gw = blk ? gw2 : gw1;
        for (int i = tid; i < 4096; i += 256)        // i = c*64+m, coalesced read
            gwT[(i & 63) * 65 + (i >> 6)] = gw[i];
        for (int i = tid; i < 3072; i += 256)        // contiguous slice
            tws[i] = tcn[(size_t)(blk + 1) * 12288 + oq * 3072 + i];
        __syncthreads();
        #pragma unroll
        for (int it = 0; it < 12; it++) {
            const int idx = tid + it * 256;          // 3072 outputs
            const int ol = idx / 192;
            const int k = idx - ol * 192;
            const int dt = k >> 6, c = k & 63;
            float s = 0.f;
            for (int m = 0; m < 64; m++)
                s += gwT[m * 65 + c] * tws[ol * 192 + m * 3 + dt];
            effT12[blk * 12288 + (oq * 16 + ol) * 192 + k] = f2h(s);
        }
    } else {
        float* tc0 = lds;                            // tcn block 0, 12288 floats
        for (int i = tid; i < 12288; i += 256) tc0[i] = tcn[i];
        for (int i = tid; i < 192; i += 256)         // i = cin*64+m
            g0T[(i & 63) * 4 + (i >> 6)] = gw0[i];
        __syncthreads();
        #pragma unroll
        for (int it = 0; it < 8; it++) {
            const int idx = tid + it * 256;          // 2048 outputs
            const int o = idx >> 5, k = idx & 31, dt = k >> 3, cin = k & 7;
            float s = 0.f;
            if (dt < 3 && cin < 3)
                for (int m = 0; m < 64; m++)
                    s += g0T[m * 4 + cin] * tc0[(o * 64 + m) * 3 + dt];
            effT0[idx] = f2h(s);
        }
        for (int i = tid; i < 192; i += 256) {
            float inv = bns[i] * rsqrtf(bnv[i] + 1e-5f);
            bnc[i] = inv;
            bnc[192 + i] = bnb[i] - bnm[i] * inv;
        }
    }
}

// ---------------------------------------------------------------------------
// Premix kernel: xg[b][tp][j*3+c] = sum_k adj[k][j] * x[b][tp-2][k][c],
// zero for pad rows.  Pitch 52 floats.  Also zeroes y2's 4 pad t-rows per b.
// ---------------------------------------------------------------------------
__global__ __launch_bounds__(256) void premix_kernel(
    const float* __restrict__ x, const float* __restrict__ adj,
    float* __restrict__ xg, short* __restrict__ y2, int cb)
{
    const int idx = blockIdx.x * 256 + threadIdx.x;
    const int total = cb * TP_DIM * K_DIM;
    if (idx < total) {
        const int b = idx / (TP_DIM * K_DIM);
        const int rem = idx - b * (TP_DIM * K_DIM);
        const int tp = rem / K_DIM, j = rem - tp * K_DIM;
        const int t = tp - 2;
        float a0 = 0.f, a1 = 0.f, a2 = 0.f;
        if (t >= 0 && t < T_DIM) {
            const float* xp = x + ((size_t)b * T_DIM + t) * 51;
            const int p0 = d_NBR_PTR[j], p1 = d_NBR_PTR[j + 1];
            for (int e = p0; e < p1; e++) {
                int k = d_NBR_K[e];
                float w = adj[k * 17 + j];
                a0 += w * xp[k * 3 + 0];
                a1 += w * xp[k * 3 + 1];
                a2 += w * xp[k * 3 + 2];
            }
        }
        float* op = xg + ((size_t)b * TP_DIM + tp) * 52 + j * 3;
        op[0] = a0; op[1] = a1; op[2] = a2;
    }
    // zero y2 pad rows: tp in {0,1,2050,2051}, 17*64 shorts each
    const int zn = cb * 4 * 1088;
    for (int z = idx; z < zn; z += gridDim.x * 256) {
        int bb = z / (4 * 1088);
        int rr = z - bb * 4 * 1088;
        int pi = rr / 1088;
        int ci = rr - pi * 1088;
        int tp = (pi < 2) ? pi : (2048 + pi);
        y2[((size_t)(bb * TP_DIM + tp) * K_DIM) * 64 + ci] = 0;
    }
}

// ---------------------------------------------------------------------------
// Kernel A: blocks 1+2 fused, f16 pipeline.  Block1 adjacency-first
// (premixed globally), block2 adjacency-last with packed-f16 mix
// (native f16x2 arithmetic -> v_pk_fma_f16).
// (256,4): VGPR cap 128, no spill.
// ---------------------------------------------------------------------------
__global__ __launch_bounds__(256, 4) void stgcn_ab_kernel(
    const float* __restrict__ xg, const float* __restrict__ adj,
    const short* __restrict__ effT0, const short* __restrict__ effT12,
    const float* __restrict__ bnc, short* __restrict__ y2)
{
    __shared__ unsigned adj_h[289];                    // f16x2 broadcast pairs
    __shared__ __align__(16) float xtg[12 * 52];       // 2496 B
    __shared__ __align__(16) short ybuf[170 * 72];     // 24480 B

    const int tid = threadIdx.x;
    const int b = blockIdx.y;
    const int t0 = blockIdx.x * 8;
    const int lane = tid & 63, wave = tid >> 6;
    const int col = lane & 15, kgrp = lane >> 4;

    for (int i = tid; i < 289; i += 256) {
        float w = adj[i];
        adj_h[i] = pkh(w, w);
    }
    {   // branch-free coalesced stage: 12 rows x 52 floats = 156 float4
        const float4* src = (const float4*)(xg + ((size_t)b * TP_DIM + t0) * 52);
        float4* dst = (float4*)xtg;
        for (int i = tid; i < 156; i += 256) dst[i] = src[i];
    }
    // weight A-frags (m-tile per wave: o = wave*16 + col)
    s16x8 af1 = *(const s16x8*)(effT0 + (wave * 16 + col) * 32 + kgrp * 8);
    s16x8 af2[6];
    #pragma unroll
    for (int kk = 0; kk < 6; kk++)
        af2[kk] = *(const s16x8*)(effT12 +
            (wave * 16 + col) * 192 + kk * 32 + kgrp * 8);
    __syncthreads();

    // ---- GEMM1: 170 rows (11 tiles), K=32; B gathered from xtg;
    //      epilogue BN+ReLU (+halo-t zero) -> y1 rows in ybuf ----
    {
        f32x4 inv4 = *(const f32x4*)&bnc[wave * 16 + kgrp * 4];
        f32x4 sh4  = *(const f32x4*)&bnc[192 + wave * 16 + kgrp * 4];
        for (int tile = 0; tile < 11; tile++) {
            const int r = tile * 16 + col;
            const int me = r < 170 ? r : 169;
            const int s = (me * 241) >> 12;     // me/17
            const int j = me - s * 17;
            int4 bz = {0, 0, 0, 0};
            if (kgrp < 3) {                      // dt = kgrp
                const float* xp = &xtg[(s + kgrp) * 52 + j * 3];
                bz.x = (int)pkh(xp[0], xp[1]);
                bz.y = (int)pkh(xp[2], 0.f);
            }
            s16x8 bfr = __builtin_bit_cast(s16x8, bz);
            f32x4 acc = __builtin_amdgcn_mfma_f32_16x16x32_f16(
                af1, bfr, (f32x4){0.f, 0.f, 0.f, 0.f}, 0, 0, 0);
            const int t = t0 - 1 + s;
            const bool valid = (t >= 0) && (t < T_DIM);
            if (r < 170) {
                float v0 = valid ? fmaxf(acc[0] * inv4[0] + sh4[0], 0.f) : 0.f;
                float v1 = valid ? fmaxf(acc[1] * inv4[1] + sh4[1], 0.f) : 0.f;
                float v2 = valid ? fmaxf(acc[2] * inv4[2] + sh4[2], 0.f) : 0.f;
                float v3 = valid ? fmaxf(acc[3] * inv4[3] + sh4[3], 0.f) : 0.f;
                u32x2 st; st[0] = pkh(v0, v1); st[1] = pkh(v2, v3);
                *(u32x2*)&ybuf[r * 72 + wave * 16 + kgrp * 4] = st;
            }
        }
    }
    __syncthreads();

    // ---- GEMM2: 136 rows (9 tiles), K=192, acc in regs ----
    f32x4 acc2[9];
    #pragma unroll
    for (int t2 = 0; t2 < 9; t2++) acc2[t2] = (f32x4){0.f, 0.f, 0.f, 0.f};
    #pragma unroll
    for (int kk = 0; kk < 6; kk++) {
        #pragma unroll
        for (int t2 = 0; t2 < 9; t2++) {
            const int r = t2 * 16 + col;
            const int me = r < 136 ? r : 135;
            s16x8 bfr = *(const s16x8*)&ybuf[
                (me + 17 * (kk >> 1)) * 72 + (kk & 1) * 32 + kgrp * 8];
            acc2[t2] = __builtin_amdgcn_mfma_f32_16x16x32_f16(
                af2[kk], bfr, acc2[t2], 0, 0, 0);
        }
    }
    // residual preload (y1 rows 17..152) into regs before overwrite
    unsigned rv[17];
    {
        const int tl = tid >> 5, o0 = (tid & 31) * 2;
        #pragma unroll
        for (int v = 0; v < 17; v++)
            rv[v] = *(const unsigned*)&ybuf[((tl + 1) * 17 + v) * 72 + o0];
    }
    __syncthreads();

    // ---- z2 -> ybuf rows 0..135 ----
    #pragma unroll
    for (int t2 = 0; t2 < 9; t2++) {
        const int r = t2 * 16 + col;
        if (r < 136) {
            u32x2 st;
            st[0] = pkh(acc2[t2][0], acc2[t2][1]);
            st[1] = pkh(acc2[t2][2], acc2[t2][3]);
            *(u32x2*)&ybuf[r * 72 + wave * 16 + kgrp * 4] = st;
        }
    }
    __syncthreads();

    // ---- mix2 (packed f16) + residual + coalesced y2 store (tp = t+2) ----
    {
        const int tl = tid >> 5, o0 = (tid & 31) * 2;
        const f16x2 inv2 = u2h(pkh(bnc[64 + o0], bnc[64 + o0 + 1]));
        const f16x2 sh2  = u2h(pkh(bnc[256 + o0], bnc[256 + o0 + 1]));
        const f16x2 zero = u2h(0u);
        f16x2 zk[17];
        #pragma unroll
        for (int k = 0; k < 17; k++)
            zk[k] = u2h(*(const unsigned*)&ybuf[(tl * 17 + k) * 72 + o0]);
        const size_t gout = ((size_t)b * TP_DIM + t0 + tl + 2) * K_DIM * 64;
        #pragma unroll
        for (int v = 0; v < 17; v++) {
            f16x2 g = zero;
            #pragma unroll
            for (int e = NBR_PTR[v]; e < NBR_PTR[v + 1]; e++) {
                int k = NBR_K[e];
                g = u2h(adj_h[k * 17 + v]) * zk[k] + g;
            }
            f16x2 val = __builtin_elementwise_max(g * inv2 + sh2, zero);
            val = val + u2h(rv[v]);
            *(unsigned*)&y2[gout + (size_t)v * 64 + o0] = h2u(val);
        }
    }
}

// ---------------------------------------------------------------------------
// Kernel B: block 3 (DIL=2) + pool, f16 pipeline.  Branch-free stage,
// GEMM3 acc regs, packed residual pre-sum, z3 overwrite, packed mix3 + pool.
// pr aliased into dead ybuf tail.  (256,4).
// ---------------------------------------------------------------------------
__global__ __launch_bounds__(256, 4) void stgcn_c_kernel(
    const short* __restrict__ y2, const float* __restrict__ adj,
    const short* __restrict__ effW3, const float* __restrict__ bnc,
    float* __restrict__ part, int b0)
{
    __shared__ unsigned adj_h[289];
    __shared__ __align__(16) short ybuf[204 * 72];     // 29376 B

    float* pr = (float*)&ybuf[136 * 72];   // alias: rows 136.. free at pool time

    const int tid = threadIdx.x;
    const int b = blockIdx.y;
    const int t0 = blockIdx.x * 8;
    const int lane = tid & 63, wave = tid >> 6;
    const int col = lane & 15, kgrp = lane >> 4;

    for (int i = tid; i < 289; i += 256) {
        float w = adj[i];
        adj_h[i] = pkh(w, w);
    }
    s16x8 af3[6];
    #pragma unroll
    for (int kk = 0; kk < 6; kk++)
        af3[kk] = *(const s16x8*)(effW3 +
            (wave * 16 + col) * 192 + kk * 32 + kgrp * 8);

    // branch-free coalesced stage: 204 rows (tp = t0 .. t0+11)
    {
        const short* base = y2 + ((size_t)b * TP_DIM + t0) * K_DIM * 64;
        for (int idx = tid; idx < 1632; idx += 256) {
            const int row = idx >> 3, c = idx & 7;
            *(s16x8*)&ybuf[row * 72 + c * 8] =
                *(const s16x8*)(base + (size_t)row * 64 + c * 8);
        }
    }
    __syncthreads();

    // ---- GEMM3: 136 rows (9 tiles), K=192, DIL=2, acc in regs ----
    f32x4 acc3[9];
    #pragma unroll
    for (int t3 = 0; t3 < 9; t3++) acc3[t3] = (f32x4){0.f, 0.f, 0.f, 0.f};
    #pragma unroll
    for (int kk = 0; kk < 6; kk++) {
        #pragma unroll
        for (int t3 = 0; t3 < 9; t3++) {
            const int r = t3 * 16 + col;
            const int me = r < 136 ? r : 135;
            s16x8 bfr = *(const s16x8*)&ybuf[
                (me + 34 * (kk >> 1)) * 72 + (kk & 1) * 32 + kgrp * 8];
            acc3[t3] = __builtin_amdgcn_mfma_f32_16x16x32_f16(
                af3[kk], bfr, acc3[t3], 0, 0, 0);
        }
    }
    // residual pre-sum (rows 34..169 = y2[t0..t0+7]), packed f16
    f16x2 rs = u2h(0u);
    {
        const int tl = tid >> 5, o0 = (tid & 31) * 2;
        #pragma unroll
        for (int v = 0; v < 17; v++)
            rs = rs + u2h(*(const unsigned*)&ybuf[((tl + 2) * 17 + v) * 72 + o0]);
    }
    __syncthreads();

    // ---- z3 -> ybuf rows 0..135 ----
    #pragma unroll
    for (int t3 = 0; t3 < 9; t3++) {
        const int r = t3 * 16 + col;
        if (r < 136) {
            u32x2 st;
            st[0] = pkh(acc3[t3][0], acc3[t3][1]);
            st[1] = pkh(acc3[t3][2], acc3[t3][3]);
            *(u32x2*)&ybuf[r * 72 + wave * 16 + kgrp * 4] = st;
        }
    }
    __syncthreads();

    // ---- mix3 (packed f16) + pool ----
    {
        const int tl = tid >> 5, o0 = (tid & 31) * 2;
        const f16x2 inv2 = u2h(pkh(bnc[128 + o0], bnc[128 + o0 + 1]));
        const f16x2 sh2  = u2h(pkh(bnc[320 + o0], bnc[320 + o0 + 1]));
        const f16x2 zero = u2h(0u);
        f16x2 zk[17];
        #pragma unroll
        for (int k = 0; k < 17; k++)
            zk[k] = u2h(*(const unsigned*)&ybuf[(tl * 17 + k) * 72 + o0]);
        float ps0 = (float)rs[0], ps1 = (float)rs[1];
        #pragma unroll
        for (int v = 0; v < 17; v++) {
            f16x2 g = zero;
            #pragma unroll
            for (int e = NBR_PTR[v]; e < NBR_PTR[v + 1]; e++) {
                int k = NBR_K[e];
                g = u2h(adj_h[k * 17 + v]) * zk[k] + g;
            }
            f16x2 val = __builtin_elementwise_max(g * inv2 + sh2, zero);
            ps0 += (float)val[0];
            ps1 += (float)val[1];
        }
        *(float2*)&pr[tl * 64 + o0] = make_float2(ps0, ps1);
    }
    __syncthreads();
    if (tid < 64) {
        float s = 0.f;
        #pragma unroll
        for (int i = 0; i < 8; i++) s += pr[i * 64 + tid];
        part[((size_t)(b0 + b) * 256 + blockIdx.x) * 64 + tid] = s;
    }
}

// ---------------------------------------------------------------------------
// Sum 256 partials per (b,c) with 256 threads, mean, LayerNorm, FC.
// ---------------------------------------------------------------------------
__global__ __launch_bounds__(256) void finish_kernel(
    const float* __restrict__ part, const float* __restrict__ ln_s,
    const float* __restrict__ ln_b, const float* __restrict__ fc_w,
    const float* __restrict__ fc_b, float* __restrict__ out)
{
    __shared__ float red[4][64];
    __shared__ float ns[64];
    const int b = blockIdx.x;
    const int g = threadIdx.x >> 6, c = threadIdx.x & 63;
    float s = 0.f;
    for (int j = 0; j < 64; j++)
        s += part[((size_t)b * 256 + g * 64 + j) * 64 + c];
    red[g][c] = s;
    __syncthreads();
    if (threadIdx.x < 64) {
        float feat = (red[0][c] + red[1][c] + red[2][c] + red[3][c])
                   / (float)(T_DIM * K_DIM);
        float m = feat;
        #pragma unroll
        for (int off = 32; off > 0; off >>= 1) m += __shfl_down(m, off);
        m = __shfl(m, 0) / 64.f;
        float d = feat - m;
        float v = d * d;
        #pragma unroll
        for (int off = 32; off > 0; off >>= 1) v += __shfl_down(v, off);
        v = __shfl(v, 0) / 64.f;
        ns[c] = d * rsqrtf(v + 1e-5f) * ln_s[c] + ln_b[c];
    }
    __syncthreads();
    if (threadIdx.x < 10) {
        float o = fc_b[threadIdx.x];
        for (int i = 0; i < 64; i++) o += ns[i] * fc_w[i * 10 + threadIdx.x];
        out[b * 10 + threadIdx.x] = o;
    }
}

// ---------------------------------------------------------------------------
extern "C" void kernel_launch(void* const* d_in, const int* in_sizes, int n_in,
                              void* d_out, int out_size, void* d_ws, size_t ws_size,
                              hipStream_t stream)
{
    const float* kpts = (const float*)d_in[0];
    const float* adj  = (const float*)d_in[1];
    const float* gw0  = (const float*)d_in[2];
    const float* gw1  = (const float*)d_in[3];
    const float* gw2  = (const float*)d_in[4];
    const float* tcn  = (const float*)d_in[5];
    const float* bns  = (const float*)d_in[6];
    const float* bnb  = (const float*)d_in[7];
    const float* bnm  = (const float*)d_in[8];
    const float* bnv  = (const float*)d_in[9];
    const float* lns  = (const float*)d_in[10];
    const float* lnb  = (const float*)d_in[11];
    const float* fcw  = (const float*)d_in[12];
    const float* fcb  = (const float*)d_in[13];
    float* out = (float*)d_out;

    // ws: bnc | part | effT0 | effT12 | xg (padded) | y2 (padded)
    float* bnc  = (float*)d_ws;
    float* part = bnc + 384;
    short* effT0  = (short*)(part + (size_t)B_DIM * 256 * 64);
    short* effT12 = effT0 + 2048;
    float* xg     = (float*)(effT12 + 24576);
    const size_t fixed_bytes = 384 * 4 + (size_t)B_DIM * 256 * 64 * 4
                             + 2048 * 2 + 24576 * 2;
    const size_t xg_per_b = (size_t)TP_DIM * 52 * 4;            // 426,816 B
    const size_t y2_per_b = (size_t)TP_DIM * K_DIM * 64 * 2;    // 4,465,152 B

    int cb = B_DIM;
    while (cb > 1 &&
           fixed_bytes + (size_t)cb * (xg_per_b + y2_per_b) > ws_size)
        cb >>= 1;
    short* y2 = (short*)(xg + (size_t)cb * TP_DIM * 52);

    fold_weights_kernel<<<9, 256, 0, stream>>>(gw0, gw1, gw2, tcn,
                                               bns, bnb, bnm, bnv,
                                               effT0, effT12, bnc);

    const int pm_blocks = (cb * TP_DIM * K_DIM + 255) / 256;
    for (int b0 = 0; b0 < B_DIM; b0 += cb) {
        premix_kernel<<<pm_blocks, 256, 0, stream>>>(
            kpts + (size_t)b0 * T_DIM * K_DIM * 3, adj, xg, y2, cb);
        stgcn_ab_kernel<<<dim3(T_DIM / 8, cb), 256, 0, stream>>>(
            xg, adj, effT0, effT12, bnc, y2);
        stgcn_c_kernel<<<dim3(T_DIM / 8, cb), 256, 0, stream>>>(
            y2, adj, effT12 + 12288, bnc, part, b0);
    }

    finish_kernel<<<B_DIM, 256, 0, stream>>>(part, lns, lnb, fcw, fcb, out);
}

// Round 17
// 230.572 us; speedup vs baseline: 2.2721x; 1.0485x over previous
//
#include <hip/hip_runtime.h>
#include <hip/hip_fp16.h>
#include <math.h>

#define T_DIM 2048
#define TP_DIM 2052                  // padded t rows: tp = t + 2, 2 pad each side
#define K_DIM 17
#define HID   64
#define B_DIM 32

typedef short s16x8 __attribute__((ext_vector_type(8)));
typedef unsigned u32x2 __attribute__((ext_vector_type(2)));
typedef float f32x4 __attribute__((ext_vector_type(4)));
typedef _Float16 f16x2 __attribute__((ext_vector_type(2)));

// packed f32 pair -> f16 pair (1 instruction: v_cvt_pkrtz_f16_f32)
__device__ __forceinline__ unsigned pkh(float lo, float hi) {
    return __builtin_bit_cast(unsigned, __builtin_amdgcn_cvt_pkrtz(lo, hi));
}
__device__ __forceinline__ f16x2 u2h(unsigned v) {
    return __builtin_bit_cast(f16x2, v);
}
__device__ __forceinline__ unsigned h2u(f16x2 v) {
    return __builtin_bit_cast(unsigned, v);
}
__device__ __forceinline__ short f2h(float f) {          // cold path
    _Float16 h = (_Float16)f;
    return __builtin_bit_cast(short, h);
}

// COCO skeleton sparsity: column-v nonzeros of adj (incl. self).
static constexpr int NBR_PTR[18] = {0,3,6,9,11,13,17,21,24,27,29,31,34,37,40,43,45,47};
static constexpr int NBR_K[47] = {
    0,1,2,  0,1,3,  0,2,4,  1,3,  2,4,
    5,6,7,11,  5,6,8,12,  5,7,9,  6,8,10,  7,9,  8,10,
    5,11,13,  6,12,14,  11,13,15,  12,14,16,  13,15,  14,16 };
__device__ const int d_NBR_PTR[18] = {0,3,6,9,11,13,17,21,24,27,29,31,34,37,40,43,45,47};
__device__ const int d_NBR_K[47] = {
    0,1,2,  0,1,3,  0,2,4,  1,3,  2,4,
    5,6,7,11,  5,6,8,12,  5,7,9,  6,8,10,  7,9,  8,10,
    5,11,13,  6,12,14,  11,13,15,  12,14,16,  13,15,  14,16 };

// ---------------------------------------------------------------------------
// Fold GCN channel-mix into temporal conv weights (f16) — ORIGINAL 64-block
// version (r12 falsified the 9-block LDS rewrite: weights are L1/L2-resident,
// and 9 blocks starved the machine; +14 us).  Extra duty: zero y2's 4 pad
// t-rows per batch (was premix's job; pads are never overwritten later).
//   effT0[o][k32]  k = dt*8+cin (cin<3, dt<3), rest 0    (block1, K=32)
//   effT12[blk][o][dt*64+c]                              (blocks 2,3, K=192)
//   bnc[blk*64+o] = s/sqrt(v+eps);  bnc[192+blk*64+o] = b - m*inv
// ---------------------------------------------------------------------------
__global__ void fold_weights_kernel(
    const float* __restrict__ gw0, const float* __restrict__ gw1,
    const float* __restrict__ gw2, const float* __restrict__ tcn,
    const float* __restrict__ bns, const float* __restrict__ bnb,
    const float* __restrict__ bnm, const float* __restrict__ bnv,
    short* __restrict__ effT0, short* __restrict__ effT12,
    float* __restrict__ bnc, short* __restrict__ y2, int cb)
{
    int tid = blockIdx.x * blockDim.x + threadIdx.x;
    int stride = gridDim.x * blockDim.x;
    for (int idx = tid; idx < 2048; idx += stride) {
        int o = idx >> 5, k = idx & 31, dt = k >> 3, cin = k & 7;
        float s = 0.f;
        if (dt < 3 && cin < 3)
            for (int m = 0; m < 64; m++)
                s += gw0[cin * 64 + m] * tcn[(o * 64 + m) * 3 + dt];
        effT0[idx] = f2h(s);
    }
    for (int idx = tid; idx < 24576; idx += stride) {
        int blk = idx / 12288;
        int r = idx - blk * 12288;
        int o = r / 192, k = r - o * 192, dt = k >> 6, c = k & 63;
        const float* gw = blk ? gw2 : gw1;
        const float* tw = tcn + (size_t)(blk + 1) * 64 * 64 * 3;
        float s = 0.f;
        for (int m = 0; m < 64; m++)
            s += gw[c * 64 + m] * tw[(o * 64 + m) * 3 + dt];
        effT12[idx] = f2h(s);
    }
    for (int i = tid; i < 192; i += stride) {
        float inv = bns[i] * rsqrtf(bnv[i] + 1e-5f);
        bnc[i] = inv;
        bnc[192 + i] = bnb[i] - bnm[i] * inv;
    }
    // zero y2 pad rows: tp in {0,1,2050,2051}, 17*64 shorts each, cb batches
    const int zn = cb * 4 * 1088;
    for (int z = tid; z < zn; z += stride) {
        int bb = z / (4 * 1088);
        int rr = z - bb * 4 * 1088;
        int pi = rr / 1088;
        int ci = rr - pi * 1088;
        int tp = (pi < 2) ? pi : (2048 + pi);
        y2[((size_t)(bb * TP_DIM + tp) * K_DIM) * 64 + ci] = 0;
    }
}

// ---------------------------------------------------------------------------
// Kernel A: premix + blocks 1+2 fused, f16 pipeline.  Premix now IN-KERNEL
// (verified in the fused-kernel arc): stage 12 raw x rows (t0-2..t0+9) with
// OOB-zero, sparse-premix into xtg in LDS.  Deletes premix_kernel + the xg
// HBM round-trip (~27 MB/iter).  Then block1 adjacency-first, block2
// adjacency-last with packed-f16 mix.  (256,4): VGPR cap 128, no spill.
// ---------------------------------------------------------------------------
__global__ __launch_bounds__(256, 4) void stgcn_ab_kernel(
    const float* __restrict__ x, const float* __restrict__ adj,
    const short* __restrict__ effT0, const short* __restrict__ effT12,
    const float* __restrict__ bnc, short* __restrict__ y2)
{
    __shared__ unsigned adj_h[289];                    // f16x2 broadcast pairs
    __shared__ float adj_f[289];
    __shared__ __align__(16) float xs[12 * 51];        // raw x rows t0-2..t0+9
    __shared__ __align__(16) float xtg[12 * 52];       // premixed, 2496 B
    __shared__ __align__(16) short ybuf[170 * 72];     // 24480 B

    const int tid = threadIdx.x;
    const int b = blockIdx.y;
    const int t0 = blockIdx.x * 8;
    const int lane = tid & 63, wave = tid >> 6;
    const int col = lane & 15, kgrp = lane >> 4;

    for (int i = tid; i < 289; i += 256) {
        float w = adj[i];
        adj_f[i] = w;
        adj_h[i] = pkh(w, w);
    }
    {   // stage raw x rows t = t0-2 .. t0+9 (zero for OOB t)
        const float* src = x + ((size_t)b * T_DIM + t0 - 2) * 51;
        for (int i = tid; i < 612; i += 256) {
            const int row = i / 51;
            const int t = t0 - 2 + row;
            xs[i] = (t >= 0 && t < T_DIM) ? src[i] : 0.f;
        }
    }
    // weight A-frags (m-tile per wave: o = wave*16 + col)
    s16x8 af1 = *(const s16x8*)(effT0 + (wave * 16 + col) * 32 + kgrp * 8);
    s16x8 af2[6];
    #pragma unroll
    for (int kk = 0; kk < 6; kk++)
        af2[kk] = *(const s16x8*)(effT12 +
            (wave * 16 + col) * 192 + kk * 32 + kgrp * 8);
    __syncthreads();

    // ---- premix: xtg[r][j*3+c] = sum_k adj[k][j] * xs[r][k*3+c], 204 items ----
    for (int i = tid; i < 204; i += 256) {
        const int r = (i * 241) >> 12;                 // i/17, valid i<204
        const int j = i - r * 17;
        const float* xp = &xs[r * 51];
        float a0 = 0.f, a1 = 0.f, a2 = 0.f;
        const int p0 = d_NBR_PTR[j], p1 = d_NBR_PTR[j + 1];
        for (int e = p0; e < p1; e++) {
            const int k = d_NBR_K[e];
            const float w = adj_f[k * 17 + j];
            a0 += w * xp[k * 3 + 0];
            a1 += w * xp[k * 3 + 1];
            a2 += w * xp[k * 3 + 2];
        }
        float* op = &xtg[r * 52 + j * 3];
        op[0] = a0; op[1] = a1; op[2] = a2;
    }
    __syncthreads();

    // ---- GEMM1: 170 rows (11 tiles), K=32; B gathered from xtg;
    //      epilogue BN+ReLU (+halo-t zero) -> y1 rows in ybuf ----
    {
        f32x4 inv4 = *(const f32x4*)&bnc[wave * 16 + kgrp * 4];
        f32x4 sh4  = *(const f32x4*)&bnc[192 + wave * 16 + kgrp * 4];
        for (int tile = 0; tile < 11; tile++) {
            const int r = tile * 16 + col;
            const int me = r < 170 ? r : 169;
            const int s = (me * 241) >> 12;     // me/17
            const int j = me - s * 17;
            int4 bz = {0, 0, 0, 0};
            if (kgrp < 3) {                      // dt = kgrp
                const float* xp = &xtg[(s + kgrp) * 52 + j * 3];
                bz.x = (int)pkh(xp[0], xp[1]);
                bz.y = (int)pkh(xp[2], 0.f);
            }
            s16x8 bfr = __builtin_bit_cast(s16x8, bz);
            f32x4 acc = __builtin_amdgcn_mfma_f32_16x16x32_f16(
                af1, bfr, (f32x4){0.f, 0.f, 0.f, 0.f}, 0, 0, 0);
            const int t = t0 - 1 + s;
            const bool valid = (t >= 0) && (t < T_DIM);
            if (r < 170) {
                float v0 = valid ? fmaxf(acc[0] * inv4[0] + sh4[0], 0.f) : 0.f;
                float v1 = valid ? fmaxf(acc[1] * inv4[1] + sh4[1], 0.f) : 0.f;
                float v2 = valid ? fmaxf(acc[2] * inv4[2] + sh4[2], 0.f) : 0.f;
                float v3 = valid ? fmaxf(acc[3] * inv4[3] + sh4[3], 0.f) : 0.f;
                u32x2 st; st[0] = pkh(v0, v1); st[1] = pkh(v2, v3);
                *(u32x2*)&ybuf[r * 72 + wave * 16 + kgrp * 4] = st;
            }
        }
    }
    __syncthreads();

    // ---- GEMM2: 136 rows (9 tiles), K=192, acc in regs ----
    f32x4 acc2[9];
    #pragma unroll
    for (int t2 = 0; t2 < 9; t2++) acc2[t2] = (f32x4){0.f, 0.f, 0.f, 0.f};
    #pragma unroll
    for (int kk = 0; kk < 6; kk++) {
        #pragma unroll
        for (int t2 = 0; t2 < 9; t2++) {
            const int r = t2 * 16 + col;
            const int me = r < 136 ? r : 135;
            s16x8 bfr = *(const s16x8*)&ybuf[
                (me + 17 * (kk >> 1)) * 72 + (kk & 1) * 32 + kgrp * 8];
            acc2[t2] = __builtin_amdgcn_mfma_f32_16x16x32_f16(
                af2[kk], bfr, acc2[t2], 0, 0, 0);
        }
    }
    // residual preload (y1 rows 17..152) into regs before overwrite
    unsigned rv[17];
    {
        const int tl = tid >> 5, o0 = (tid & 31) * 2;
        #pragma unroll
        for (int v = 0; v < 17; v++)
            rv[v] = *(const unsigned*)&ybuf[((tl + 1) * 17 + v) * 72 + o0];
    }
    __syncthreads();

    // ---- z2 -> ybuf rows 0..135 ----
    #pragma unroll
    for (int t2 = 0; t2 < 9; t2++) {
        const int r = t2 * 16 + col;
        if (r < 136) {
            u32x2 st;
            st[0] = pkh(acc2[t2][0], acc2[t2][1]);
            st[1] = pkh(acc2[t2][2], acc2[t2][3]);
            *(u32x2*)&ybuf[r * 72 + wave * 16 + kgrp * 4] = st;
        }
    }
    __syncthreads();

    // ---- mix2 (packed f16) + residual + coalesced y2 store (tp = t+2) ----
    {
        const int tl = tid >> 5, o0 = (tid & 31) * 2;
        const f16x2 inv2 = u2h(pkh(bnc[64 + o0], bnc[64 + o0 + 1]));
        const f16x2 sh2  = u2h(pkh(bnc[256 + o0], bnc[256 + o0 + 1]));
        const f16x2 zero = u2h(0u);
        f16x2 zk[17];
        #pragma unroll
        for (int k = 0; k < 17; k++)
            zk[k] = u2h(*(const unsigned*)&ybuf[(tl * 17 + k) * 72 + o0]);
        const size_t gout = ((size_t)b * TP_DIM + t0 + tl + 2) * K_DIM * 64;
        #pragma unroll
        for (int v = 0; v < 17; v++) {
            f16x2 g = zero;
            #pragma unroll
            for (int e = NBR_PTR[v]; e < NBR_PTR[v + 1]; e++) {
                int k = NBR_K[e];
                g = u2h(adj_h[k * 17 + v]) * zk[k] + g;
            }
            f16x2 val = __builtin_elementwise_max(g * inv2 + sh2, zero);
            val = val + u2h(rv[v]);
            *(unsigned*)&y2[gout + (size_t)v * 64 + o0] = h2u(val);
        }
    }
}

// ---------------------------------------------------------------------------
// Kernel B: block 3 (DIL=2) + pool, f16 pipeline.  Branch-free stage,
// GEMM3 acc regs, packed residual pre-sum, z3 overwrite, packed mix3 + pool.
// pr aliased into dead ybuf tail.  (256,4).
// ---------------------------------------------------------------------------
__global__ __launch_bounds__(256, 4) void stgcn_c_kernel(
    const short* __restrict__ y2, const float* __restrict__ adj,
    const short* __restrict__ effW3, const float* __restrict__ bnc,
    float* __restrict__ part, int b0)
{
    __shared__ unsigned adj_h[289];
    __shared__ __align__(16) short ybuf[204 * 72];     // 29376 B

    float* pr = (float*)&ybuf[136 * 72];   // alias: rows 136.. free at pool time

    const int tid = threadIdx.x;
    const int b = blockIdx.y;
    const int t0 = blockIdx.x * 8;
    const int lane = tid & 63, wave = tid >> 6;
    const int col = lane & 15, kgrp = lane >> 4;

    for (int i = tid; i < 289; i += 256) {
        float w = adj[i];
        adj_h[i] = pkh(w, w);
    }
    s16x8 af3[6];
    #pragma unroll
    for (int kk = 0; kk < 6; kk++)
        af3[kk] = *(const s16x8*)(effW3 +
            (wave * 16 + col) * 192 + kk * 32 + kgrp * 8);

    // branch-free coalesced stage: 204 rows (tp = t0 .. t0+11)
    {
        const short* base = y2 + ((size_t)b * TP_DIM + t0) * K_DIM * 64;
        for (int idx = tid; idx < 1632; idx += 256) {
            const int row = idx >> 3, c = idx & 7;
            *(s16x8*)&ybuf[row * 72 + c * 8] =
                *(const s16x8*)(base + (size_t)row * 64 + c * 8);
        }
    }
    __syncthreads();

    // ---- GEMM3: 136 rows (9 tiles), K=192, DIL=2, acc in regs ----
    f32x4 acc3[9];
    #pragma unroll
    for (int t3 = 0; t3 < 9; t3++) acc3[t3] = (f32x4){0.f, 0.f, 0.f, 0.f};
    #pragma unroll
    for (int kk = 0; kk < 6; kk++) {
        #pragma unroll
        for (int t3 = 0; t3 < 9; t3++) {
            const int r = t3 * 16 + col;
            const int me = r < 136 ? r : 135;
            s16x8 bfr = *(const s16x8*)&ybuf[
                (me + 34 * (kk >> 1)) * 72 + (kk & 1) * 32 + kgrp * 8];
            acc3[t3] = __builtin_amdgcn_mfma_f32_16x16x32_f16(
                af3[kk], bfr, acc3[t3], 0, 0, 0);
        }
    }
    // residual pre-sum (rows 34..169 = y2[t0..t0+7]), packed f16
    f16x2 rs = u2h(0u);
    {
        const int tl = tid >> 5, o0 = (tid & 31) * 2;
        #pragma unroll
        for (int v = 0; v < 17; v++)
            rs = rs + u2h(*(const unsigned*)&ybuf[((tl + 2) * 17 + v) * 72 + o0]);
    }
    __syncthreads();

    // ---- z3 -> ybuf rows 0..135 ----
    #pragma unroll
    for (int t3 = 0; t3 < 9; t3++) {
        const int r = t3 * 16 + col;
        if (r < 136) {
            u32x2 st;
            st[0] = pkh(acc3[t3][0], acc3[t3][1]);
            st[1] = pkh(acc3[t3][2], acc3[t3][3]);
            *(u32x2*)&ybuf[r * 72 + wave * 16 + kgrp * 4] = st;
        }
    }
    __syncthreads();

    // ---- mix3 (packed f16) + pool ----
    {
        const int tl = tid >> 5, o0 = (tid & 31) * 2;
        const f16x2 inv2 = u2h(pkh(bnc[128 + o0], bnc[128 + o0 + 1]));
        const f16x2 sh2  = u2h(pkh(bnc[320 + o0], bnc[320 + o0 + 1]));
        const f16x2 zero = u2h(0u);
        f16x2 zk[17];
        #pragma unroll
        for (int k = 0; k < 17; k++)
            zk[k] = u2h(*(const unsigned*)&ybuf[(tl * 17 + k) * 72 + o0]);
        float ps0 = (float)rs[0], ps1 = (float)rs[1];
        #pragma unroll
        for (int v = 0; v < 17; v++) {
            f16x2 g = zero;
            #pragma unroll
            for (int e = NBR_PTR[v]; e < NBR_PTR[v + 1]; e++) {
                int k = NBR_K[e];
                g = u2h(adj_h[k * 17 + v]) * zk[k] + g;
            }
            f16x2 val = __builtin_elementwise_max(g * inv2 + sh2, zero);
            ps0 += (float)val[0];
            ps1 += (float)val[1];
        }
        *(float2*)&pr[tl * 64 + o0] = make_float2(ps0, ps1);
    }
    __syncthreads();
    if (tid < 64) {
        float s = 0.f;
        #pragma unroll
        for (int i = 0; i < 8; i++) s += pr[i * 64 + tid];
        part[((size_t)(b0 + b) * 256 + blockIdx.x) * 64 + tid] = s;
    }
}

// ---------------------------------------------------------------------------
// Sum 256 partials per (b,c) with 256 threads, mean, LayerNorm, FC.
// ---------------------------------------------------------------------------
__global__ __launch_bounds__(256) void finish_kernel(
    const float* __restrict__ part, const float* __restrict__ ln_s,
    const float* __restrict__ ln_b, const float* __restrict__ fc_w,
    const float* __restrict__ fc_b, float* __restrict__ out)
{
    __shared__ float red[4][64];
    __shared__ float ns[64];
    const int b = blockIdx.x;
    const int g = threadIdx.x >> 6, c = threadIdx.x & 63;
    float s = 0.f;
    for (int j = 0; j < 64; j++)
        s += part[((size_t)b * 256 + g * 64 + j) * 64 + c];
    red[g][c] = s;
    __syncthreads();
    if (threadIdx.x < 64) {
        float feat = (red[0][c] + red[1][c] + red[2][c] + red[3][c])
                   / (float)(T_DIM * K_DIM);
        float m = feat;
        #pragma unroll
        for (int off = 32; off > 0; off >>= 1) m += __shfl_down(m, off);
        m = __shfl(m, 0) / 64.f;
        float d = feat - m;
        float v = d * d;
        #pragma unroll
        for (int off = 32; off > 0; off >>= 1) v += __shfl_down(v, off);
        v = __shfl(v, 0) / 64.f;
        ns[c] = d * rsqrtf(v + 1e-5f) * ln_s[c] + ln_b[c];
    }
    __syncthreads();
    if (threadIdx.x < 10) {
        float o = fc_b[threadIdx.x];
        for (int i = 0; i < 64; i++) o += ns[i] * fc_w[i * 10 + threadIdx.x];
        out[b * 10 + threadIdx.x] = o;
    }
}

// ---------------------------------------------------------------------------
extern "C" void kernel_launch(void* const* d_in, const int* in_sizes, int n_in,
                              void* d_out, int out_size, void* d_ws, size_t ws_size,
                              hipStream_t stream)
{
    const float* kpts = (const float*)d_in[0];
    const float* adj  = (const float*)d_in[1];
    const float* gw0  = (const float*)d_in[2];
    const float* gw1  = (const float*)d_in[3];
    const float* gw2  = (const float*)d_in[4];
    const float* tcn  = (const float*)d_in[5];
    const float* bns  = (const float*)d_in[6];
    const float* bnb  = (const float*)d_in[7];
    const float* bnm  = (const float*)d_in[8];
    const float* bnv  = (const float*)d_in[9];
    const float* lns  = (const float*)d_in[10];
    const float* lnb  = (const float*)d_in[11];
    const float* fcw  = (const float*)d_in[12];
    const float* fcb  = (const float*)d_in[13];
    float* out = (float*)d_out;

    // ws: bnc | part | effT0 | effT12 | y2 (padded)  — xg buffer removed
    float* bnc  = (float*)d_ws;
    float* part = bnc + 384;
    short* effT0  = (short*)(part + (size_t)B_DIM * 256 * 64);
    short* effT12 = effT0 + 2048;
    short* y2     = effT12 + 24576;
    const size_t fixed_bytes = 384 * 4 + (size_t)B_DIM * 256 * 64 * 4
                             + 2048 * 2 + 24576 * 2;
    const size_t y2_per_b = (size_t)TP_DIM * K_DIM * 64 * 2;    // 4,465,152 B

    int cb = B_DIM;
    while (cb > 1 && fixed_bytes + (size_t)cb * y2_per_b > ws_size)
        cb >>= 1;

    fold_weights_kernel<<<64, 256, 0, stream>>>(gw0, gw1, gw2, tcn,
                                                bns, bnb, bnm, bnv,
                                                effT0, effT12, bnc, y2, cb);

    for (int b0 = 0; b0 < B_DIM; b0 += cb) {
        stgcn_ab_kernel<<<dim3(T_DIM / 8, cb), 256, 0, stream>>>(
            kpts + (size_t)b0 * T_DIM * K_DIM * 3, adj, effT0, effT12, bnc, y2);
        stgcn_c_kernel<<<dim3(T_DIM / 8, cb), 256, 0, stream>>>(
            y2, adj, effT12 + 12288, bnc, part, b0);
    }

    finish_kernel<<<B_DIM, 256, 0, stream>>>(part, lns, lnb, fcw, fcb, out);
}

// Round 18
// 227.270 us; speedup vs baseline: 2.3051x; 1.0145x over previous
//
#include <hip/hip_runtime.h>
#include <hip/hip_fp16.h>
#include <math.h>

#define T_DIM 2048
#define TP_DIM 2052                  // padded t rows: tp = t + 2, 2 pad each side
#define K_DIM 17
#define HID   64
#define B_DIM 32

typedef short s16x8 __attribute__((ext_vector_type(8)));
typedef unsigned u32x2 __attribute__((ext_vector_type(2)));
typedef float f32x4 __attribute__((ext_vector_type(4)));
typedef _Float16 f16x2 __attribute__((ext_vector_type(2)));

// packed f32 pair -> f16 pair (1 instruction: v_cvt_pkrtz_f16_f32)
__device__ __forceinline__ unsigned pkh(float lo, float hi) {
    return __builtin_bit_cast(unsigned, __builtin_amdgcn_cvt_pkrtz(lo, hi));
}
__device__ __forceinline__ f16x2 u2h(unsigned v) {
    return __builtin_bit_cast(f16x2, v);
}
__device__ __forceinline__ unsigned h2u(f16x2 v) {
    return __builtin_bit_cast(unsigned, v);
}
__device__ __forceinline__ short f2h(float f) {          // cold path
    _Float16 h = (_Float16)f;
    return __builtin_bit_cast(short, h);
}

// COCO skeleton sparsity: column-v nonzeros of adj (incl. self).
static constexpr int NBR_PTR[18] = {0,3,6,9,11,13,17,21,24,27,29,31,34,37,40,43,45,47};
static constexpr int NBR_K[47] = {
    0,1,2,  0,1,3,  0,2,4,  1,3,  2,4,
    5,6,7,11,  5,6,8,12,  5,7,9,  6,8,10,  7,9,  8,10,
    5,11,13,  6,12,14,  11,13,15,  12,14,16,  13,15,  14,16 };
__device__ const int d_NBR_PTR[18] = {0,3,6,9,11,13,17,21,24,27,29,31,34,37,40,43,45,47};
__device__ const int d_NBR_K[47] = {
    0,1,2,  0,1,3,  0,2,4,  1,3,  2,4,
    5,6,7,11,  5,6,8,12,  5,7,9,  6,8,10,  7,9,  8,10,
    5,11,13,  6,12,14,  11,13,15,  12,14,16,  13,15,  14,16 };

// ---------------------------------------------------------------------------
// Fold GCN channel-mix into temporal conv weights (f16) — ORIGINAL 64-block
// version.  Extra duty: zero y2's 4 pad t-rows per batch.
//   effT0[o][k32]  k = dt*8+cin (cin<3, dt<3), rest 0    (block1, K=32)
//   effT12[blk][o][dt*64+c]                              (blocks 2,3, K=192)
//   bnc[blk*64+o] = s/sqrt(v+eps);  bnc[192+blk*64+o] = b - m*inv
// ---------------------------------------------------------------------------
__global__ void fold_weights_kernel(
    const float* __restrict__ gw0, const float* __restrict__ gw1,
    const float* __restrict__ gw2, const float* __restrict__ tcn,
    const float* __restrict__ bns, const float* __restrict__ bnb,
    const float* __restrict__ bnm, const float* __restrict__ bnv,
    short* __restrict__ effT0, short* __restrict__ effT12,
    float* __restrict__ bnc, short* __restrict__ y2, int cb)
{
    int tid = blockIdx.x * blockDim.x + threadIdx.x;
    int stride = gridDim.x * blockDim.x;
    for (int idx = tid; idx < 2048; idx += stride) {
        int o = idx >> 5, k = idx & 31, dt = k >> 3, cin = k & 7;
        float s = 0.f;
        if (dt < 3 && cin < 3)
            for (int m = 0; m < 64; m++)
                s += gw0[cin * 64 + m] * tcn[(o * 64 + m) * 3 + dt];
        effT0[idx] = f2h(s);
    }
    for (int idx = tid; idx < 24576; idx += stride) {
        int blk = idx / 12288;
        int r = idx - blk * 12288;
        int o = r / 192, k = r - o * 192, dt = k >> 6, c = k & 63;
        const float* gw = blk ? gw2 : gw1;
        const float* tw = tcn + (size_t)(blk + 1) * 64 * 64 * 3;
        float s = 0.f;
        for (int m = 0; m < 64; m++)
            s += gw[c * 64 + m] * tw[(o * 64 + m) * 3 + dt];
        effT12[idx] = f2h(s);
    }
    for (int i = tid; i < 192; i += stride) {
        float inv = bns[i] * rsqrtf(bnv[i] + 1e-5f);
        bnc[i] = inv;
        bnc[192 + i] = bnb[i] - bnm[i] * inv;
    }
    // zero y2 pad rows: tp in {0,1,2050,2051}, 17*64 shorts each, cb batches
    const int zn = cb * 4 * 1088;
    for (int z = tid; z < zn; z += stride) {
        int bb = z / (4 * 1088);
        int rr = z - bb * 4 * 1088;
        int pi = rr / 1088;
        int ci = rr - pi * 1088;
        int tp = (pi < 2) ? pi : (2048 + pi);
        y2[((size_t)(bb * TP_DIM + tp) * K_DIM) * 64 + ci] = 0;
    }
}

// ---------------------------------------------------------------------------
// Kernel A: premix + blocks 1+2 fused, f16 pipeline.  Premix reads DIRECTLY
// from global x + adj (both L1/L3-resident) -> xtg, concurrent with adj_h /
// A-frag loads, ONE barrier before GEMM1.  (r17's staged-copy + 2 barriers
// added ~22 us of serial head; this removes the stage and one barrier.)
// Then block1 adjacency-first, block2 adjacency-last with packed-f16 mix.
// (256,4): VGPR cap 128, no spill.
// ---------------------------------------------------------------------------
__global__ __launch_bounds__(256, 4) void stgcn_ab_kernel(
    const float* __restrict__ x, const float* __restrict__ adj,
    const short* __restrict__ effT0, const short* __restrict__ effT12,
    const float* __restrict__ bnc, short* __restrict__ y2)
{
    __shared__ unsigned adj_h[289];                    // f16x2 broadcast pairs
    __shared__ __align__(16) float xtg[12 * 52];       // premixed, 2496 B
    __shared__ __align__(16) short ybuf[170 * 72];     // 24480 B

    const int tid = threadIdx.x;
    const int b = blockIdx.y;
    const int t0 = blockIdx.x * 8;
    const int lane = tid & 63, wave = tid >> 6;
    const int col = lane & 15, kgrp = lane >> 4;

    for (int i = tid; i < 289; i += 256) {
        float w = adj[i];
        adj_h[i] = pkh(w, w);
    }
    // weight A-frags (m-tile per wave: o = wave*16 + col)
    s16x8 af1 = *(const s16x8*)(effT0 + (wave * 16 + col) * 32 + kgrp * 8);
    s16x8 af2[6];
    #pragma unroll
    for (int kk = 0; kk < 6; kk++)
        af2[kk] = *(const s16x8*)(effT12 +
            (wave * 16 + col) * 192 + kk * 32 + kgrp * 8);

    // ---- premix from GLOBAL: xtg[r][j*3+c] = sum_k adj[k][j]*x[t0-2+r][k][c],
    //      zero for OOB t.  204 items, no LDS dependency -> no prior barrier.
    for (int i = tid; i < 204; i += 256) {
        const int r = (i * 241) >> 12;                 // i/17, valid i<204
        const int j = i - r * 17;
        const int t = t0 - 2 + r;
        float a0 = 0.f, a1 = 0.f, a2 = 0.f;
        if (t >= 0 && t < T_DIM) {
            const float* xp = x + ((size_t)b * T_DIM + t) * 51;
            const int p0 = d_NBR_PTR[j], p1 = d_NBR_PTR[j + 1];
            for (int e = p0; e < p1; e++) {
                const int k = d_NBR_K[e];
                const float w = adj[k * 17 + j];
                a0 += w * xp[k * 3 + 0];
                a1 += w * xp[k * 3 + 1];
                a2 += w * xp[k * 3 + 2];
            }
        }
        float* op = &xtg[r * 52 + j * 3];
        op[0] = a0; op[1] = a1; op[2] = a2;
    }
    __syncthreads();

    // ---- GEMM1: 170 rows (11 tiles), K=32; B gathered from xtg;
    //      epilogue BN+ReLU (+halo-t zero) -> y1 rows in ybuf ----
    {
        f32x4 inv4 = *(const f32x4*)&bnc[wave * 16 + kgrp * 4];
        f32x4 sh4  = *(const f32x4*)&bnc[192 + wave * 16 + kgrp * 4];
        for (int tile = 0; tile < 11; tile++) {
            const int r = tile * 16 + col;
            const int me = r < 170 ? r : 169;
            const int s = (me * 241) >> 12;     // me/17
            const int j = me - s * 17;
            int4 bz = {0, 0, 0, 0};
            if (kgrp < 3) {                      // dt = kgrp
                const float* xp = &xtg[(s + kgrp) * 52 + j * 3];
                bz.x = (int)pkh(xp[0], xp[1]);
                bz.y = (int)pkh(xp[2], 0.f);
            }
            s16x8 bfr = __builtin_bit_cast(s16x8, bz);
            f32x4 acc = __builtin_amdgcn_mfma_f32_16x16x32_f16(
                af1, bfr, (f32x4){0.f, 0.f, 0.f, 0.f}, 0, 0, 0);
            const int t = t0 - 1 + s;
            const bool valid = (t >= 0) && (t < T_DIM);
            if (r < 170) {
                float v0 = valid ? fmaxf(acc[0] * inv4[0] + sh4[0], 0.f) : 0.f;
                float v1 = valid ? fmaxf(acc[1] * inv4[1] + sh4[1], 0.f) : 0.f;
                float v2 = valid ? fmaxf(acc[2] * inv4[2] + sh4[2], 0.f) : 0.f;
                float v3 = valid ? fmaxf(acc[3] * inv4[3] + sh4[3], 0.f) : 0.f;
                u32x2 st; st[0] = pkh(v0, v1); st[1] = pkh(v2, v3);
                *(u32x2*)&ybuf[r * 72 + wave * 16 + kgrp * 4] = st;
            }
        }
    }
    __syncthreads();

    // ---- GEMM2: 136 rows (9 tiles), K=192, acc in regs ----
    f32x4 acc2[9];
    #pragma unroll
    for (int t2 = 0; t2 < 9; t2++) acc2[t2] = (f32x4){0.f, 0.f, 0.f, 0.f};
    #pragma unroll
    for (int kk = 0; kk < 6; kk++) {
        #pragma unroll
        for (int t2 = 0; t2 < 9; t2++) {
            const int r = t2 * 16 + col;
            const int me = r < 136 ? r : 135;
            s16x8 bfr = *(const s16x8*)&ybuf[
                (me + 17 * (kk >> 1)) * 72 + (kk & 1) * 32 + kgrp * 8];
            acc2[t2] = __builtin_amdgcn_mfma_f32_16x16x32_f16(
                af2[kk], bfr, acc2[t2], 0, 0, 0);
        }
    }
    // residual preload (y1 rows 17..152) into regs before overwrite
    unsigned rv[17];
    {
        const int tl = tid >> 5, o0 = (tid & 31) * 2;
        #pragma unroll
        for (int v = 0; v < 17; v++)
            rv[v] = *(const unsigned*)&ybuf[((tl + 1) * 17 + v) * 72 + o0];
    }
    __syncthreads();

    // ---- z2 -> ybuf rows 0..135 ----
    #pragma unroll
    for (int t2 = 0; t2 < 9; t2++) {
        const int r = t2 * 16 + col;
        if (r < 136) {
            u32x2 st;
            st[0] = pkh(acc2[t2][0], acc2[t2][1]);
            st[1] = pkh(acc2[t2][2], acc2[t2][3]);
            *(u32x2*)&ybuf[r * 72 + wave * 16 + kgrp * 4] = st;
        }
    }
    __syncthreads();

    // ---- mix2 (packed f16) + residual + coalesced y2 store (tp = t+2) ----
    {
        const int tl = tid >> 5, o0 = (tid & 31) * 2;
        const f16x2 inv2 = u2h(pkh(bnc[64 + o0], bnc[64 + o0 + 1]));
        const f16x2 sh2  = u2h(pkh(bnc[256 + o0], bnc[256 + o0 + 1]));
        const f16x2 zero = u2h(0u);
        f16x2 zk[17];
        #pragma unroll
        for (int k = 0; k < 17; k++)
            zk[k] = u2h(*(const unsigned*)&ybuf[(tl * 17 + k) * 72 + o0]);
        const size_t gout = ((size_t)b * TP_DIM + t0 + tl + 2) * K_DIM * 64;
        #pragma unroll
        for (int v = 0; v < 17; v++) {
            f16x2 g = zero;
            #pragma unroll
            for (int e = NBR_PTR[v]; e < NBR_PTR[v + 1]; e++) {
                int k = NBR_K[e];
                g = u2h(adj_h[k * 17 + v]) * zk[k] + g;
            }
            f16x2 val = __builtin_elementwise_max(g * inv2 + sh2, zero);
            val = val + u2h(rv[v]);
            *(unsigned*)&y2[gout + (size_t)v * 64 + o0] = h2u(val);
        }
    }
}

// ---------------------------------------------------------------------------
// Kernel B: block 3 (DIL=2) + pool, f16 pipeline.  Branch-free stage,
// GEMM3 acc regs, packed residual pre-sum, z3 overwrite, packed mix3 + pool.
// pr aliased into dead ybuf tail.  (256,4).
// ---------------------------------------------------------------------------
__global__ __launch_bounds__(256, 4) void stgcn_c_kernel(
    const short* __restrict__ y2, const float* __restrict__ adj,
    const short* __restrict__ effW3, const float* __restrict__ bnc,
    float* __restrict__ part, int b0)
{
    __shared__ unsigned adj_h[289];
    __shared__ __align__(16) short ybuf[204 * 72];     // 29376 B

    float* pr = (float*)&ybuf[136 * 72];   // alias: rows 136.. free at pool time

    const int tid = threadIdx.x;
    const int b = blockIdx.y;
    const int t0 = blockIdx.x * 8;
    const int lane = tid & 63, wave = tid >> 6;
    const int col = lane & 15, kgrp = lane >> 4;

    for (int i = tid; i < 289; i += 256) {
        float w = adj[i];
        adj_h[i] = pkh(w, w);
    }
    s16x8 af3[6];
    #pragma unroll
    for (int kk = 0; kk < 6; kk++)
        af3[kk] = *(const s16x8*)(effW3 +
            (wave * 16 + col) * 192 + kk * 32 + kgrp * 8);

    // branch-free coalesced stage: 204 rows (tp = t0 .. t0+11)
    {
        const short* base = y2 + ((size_t)b * TP_DIM + t0) * K_DIM * 64;
        for (int idx = tid; idx < 1632; idx += 256) {
            const int row = idx >> 3, c = idx & 7;
            *(s16x8*)&ybuf[row * 72 + c * 8] =
                *(const s16x8*)(base + (size_t)row * 64 + c * 8);
        }
    }
    __syncthreads();

    // ---- GEMM3: 136 rows (9 tiles), K=192, DIL=2, acc in regs ----
    f32x4 acc3[9];
    #pragma unroll
    for (int t3 = 0; t3 < 9; t3++) acc3[t3] = (f32x4){0.f, 0.f, 0.f, 0.f};
    #pragma unroll
    for (int kk = 0; kk < 6; kk++) {
        #pragma unroll
        for (int t3 = 0; t3 < 9; t3++) {
            const int r = t3 * 16 + col;
            const int me = r < 136 ? r : 135;
            s16x8 bfr = *(const s16x8*)&ybuf[
                (me + 34 * (kk >> 1)) * 72 + (kk & 1) * 32 + kgrp * 8];
            acc3[t3] = __builtin_amdgcn_mfma_f32_16x16x32_f16(
                af3[kk], bfr, acc3[t3], 0, 0, 0);
        }
    }
    // residual pre-sum (rows 34..169 = y2[t0..t0+7]), packed f16
    f16x2 rs = u2h(0u);
    {
        const int tl = tid >> 5, o0 = (tid & 31) * 2;
        #pragma unroll
        for (int v = 0; v < 17; v++)
            rs = rs + u2h(*(const unsigned*)&ybuf[((tl + 2) * 17 + v) * 72 + o0]);
    }
    __syncthreads();

    // ---- z3 -> ybuf rows 0..135 ----
    #pragma unroll
    for (int t3 = 0; t3 < 9; t3++) {
        const int r = t3 * 16 + col;
        if (r < 136) {
            u32x2 st;
            st[0] = pkh(acc3[t3][0], acc3[t3][1]);
            st[1] = pkh(acc3[t3][2], acc3[t3][3]);
            *(u32x2*)&ybuf[r * 72 + wave * 16 + kgrp * 4] = st;
        }
    }
    __syncthreads();

    // ---- mix3 (packed f16) + pool ----
    {
        const int tl = tid >> 5, o0 = (tid & 31) * 2;
        const f16x2 inv2 = u2h(pkh(bnc[128 + o0], bnc[128 + o0 + 1]));
        const f16x2 sh2  = u2h(pkh(bnc[320 + o0], bnc[320 + o0 + 1]));
        const f16x2 zero = u2h(0u);
        f16x2 zk[17];
        #pragma unroll
        for (int k = 0; k < 17; k++)
            zk[k] = u2h(*(const unsigned*)&ybuf[(tl * 17 + k) * 72 + o0]);
        float ps0 = (float)rs[0], ps1 = (float)rs[1];
        #pragma unroll
        for (int v = 0; v < 17; v++) {
            f16x2 g = zero;
            #pragma unroll
            for (int e = NBR_PTR[v]; e < NBR_PTR[v + 1]; e++) {
                int k = NBR_K[e];
                g = u2h(adj_h[k * 17 + v]) * zk[k] + g;
            }
            f16x2 val = __builtin_elementwise_max(g * inv2 + sh2, zero);
            ps0 += (float)val[0];
            ps1 += (float)val[1];
        }
        *(float2*)&pr[tl * 64 + o0] = make_float2(ps0, ps1);
    }
    __syncthreads();
    if (tid < 64) {
        float s = 0.f;
        #pragma unroll
        for (int i = 0; i < 8; i++) s += pr[i * 64 + tid];
        part[((size_t)(b0 + b) * 256 + blockIdx.x) * 64 + tid] = s;
    }
}

// ---------------------------------------------------------------------------
// Sum 256 partials per (b,c) with 256 threads, mean, LayerNorm, FC.
// ---------------------------------------------------------------------------
__global__ __launch_bounds__(256) void finish_kernel(
    const float* __restrict__ part, const float* __restrict__ ln_s,
    const float* __restrict__ ln_b, const float* __restrict__ fc_w,
    const float* __restrict__ fc_b, float* __restrict__ out)
{
    __shared__ float red[4][64];
    __shared__ float ns[64];
    const int b = blockIdx.x;
    const int g = threadIdx.x >> 6, c = threadIdx.x & 63;
    float s = 0.f;
    for (int j = 0; j < 64; j++)
        s += part[((size_t)b * 256 + g * 64 + j) * 64 + c];
    red[g][c] = s;
    __syncthreads();
    if (threadIdx.x < 64) {
        float feat = (red[0][c] + red[1][c] + red[2][c] + red[3][c])
                   / (float)(T_DIM * K_DIM);
        float m = feat;
        #pragma unroll
        for (int off = 32; off > 0; off >>= 1) m += __shfl_down(m, off);
        m = __shfl(m, 0) / 64.f;
        float d = feat - m;
        float v = d * d;
        #pragma unroll
        for (int off = 32; off > 0; off >>= 1) v += __shfl_down(v, off);
        v = __shfl(v, 0) / 64.f;
        ns[c] = d * rsqrtf(v + 1e-5f) * ln_s[c] + ln_b[c];
    }
    __syncthreads();
    if (threadIdx.x < 10) {
        float o = fc_b[threadIdx.x];
        for (int i = 0; i < 64; i++) o += ns[i] * fc_w[i * 10 + threadIdx.x];
        out[b * 10 + threadIdx.x] = o;
    }
}

// ---------------------------------------------------------------------------
extern "C" void kernel_launch(void* const* d_in, const int* in_sizes, int n_in,
                              void* d_out, int out_size, void* d_ws, size_t ws_size,
                              hipStream_t stream)
{
    const float* kpts = (const float*)d_in[0];
    const float* adj  = (const float*)d_in[1];
    const float* gw0  = (const float*)d_in[2];
    const float* gw1  = (const float*)d_in[3];
    const float* gw2  = (const float*)d_in[4];
    const float* tcn  = (const float*)d_in[5];
    const float* bns  = (const float*)d_in[6];
    const float* bnb  = (const float*)d_in[7];
    const float* bnm  = (const float*)d_in[8];
    const float* bnv  = (const float*)d_in[9];
    const float* lns  = (const float*)d_in[10];
    const float* lnb  = (const float*)d_in[11];
    const float* fcw  = (const float*)d_in[12];
    const float* fcb  = (const float*)d_in[13];
    float* out = (float*)d_out;

    // ws: bnc | part | effT0 | effT12 | y2 (padded)
    float* bnc  = (float*)d_ws;
    float* part = bnc + 384;
    short* effT0  = (short*)(part + (size_t)B_DIM * 256 * 64);
    short* effT12 = effT0 + 2048;
    short* y2     = effT12 + 24576;
    const size_t fixed_bytes = 384 * 4 + (size_t)B_DIM * 256 * 64 * 4
                             + 2048 * 2 + 24576 * 2;
    const size_t y2_per_b = (size_t)TP_DIM * K_DIM * 64 * 2;    // 4,465,152 B

    int cb = B_DIM;
    while (cb > 1 && fixed_bytes + (size_t)cb * y2_per_b > ws_size)
        cb >>= 1;

    fold_weights_kernel<<<64, 256, 0, stream>>>(gw0, gw1, gw2, tcn,
                                                bns, bnb, bnm, bnv,
                                                effT0, effT12, bnc, y2, cb);

    for (int b0 = 0; b0 < B_DIM; b0 += cb) {
        stgcn_ab_kernel<<<dim3(T_DIM / 8, cb), 256, 0, stream>>>(
            kpts + (size_t)b0 * T_DIM * K_DIM * 3, adj, effT0, effT12, bnc, y2);
        stgcn_c_kernel<<<dim3(T_DIM / 8, cb), 256, 0, stream>>>(
            y2, adj, effT12 + 12288, bnc, part, b0);
    }

    finish_kernel<<<B_DIM, 256, 0, stream>>>(part, lns, lnb, fcw, fcb, out);
}